// Round 1
// baseline (814.678 us; speedup 1.0000x reference)
//
#include <hip/hip_runtime.h>
#include <hip/hip_bf16.h>

namespace {

constexpr int Bb = 512;
constexpr int Tt = 512;
constexpr int OD = 32;
constexpr int AD = 8;
constexpr int WL = 10;
constexpr int Nn = Tt - WL + 1;   // 503
constexpr int CH = OD + AD;       // 40

constexpr long SZ_PO = (long)Bb * Nn * 32;   // 8,241,152
constexpr long SZ_PR = (long)Bb * Nn * 2;    // 515,072
constexpr long OFF_POST   = 0;
constexpr long OFF_PRIORS = SZ_PO;
constexpr long OFF_POSTS  = OFF_PRIORS + SZ_PR;
constexpr long OFF_XTRAJ  = OFF_POSTS + SZ_PR;
constexpr long OFF_TGT    = OFF_XTRAJ + SZ_PR;
constexpr long OFF_LAB    = OFF_TGT + SZ_PO;

__device__ __forceinline__ float sigmoidf_(float x) {
  return 1.0f / (1.0f + __expf(-x));
}
__device__ __forceinline__ float tanh_(float x) {
  // 1 - 2/(exp(2x)+1); exact at +-inf saturation
  return 1.0f - 2.0f / (__expf(2.0f * x) + 1.0f);
}

// ---------------- copies: target_obs_traj + labels ----------------
__global__ void copy_kernel(const float* __restrict__ obs,
                            const int* __restrict__ tlab,
                            float* __restrict__ out) {
  const int total4 = (int)(SZ_PO / 4);      // float4 count for target_obs
  const int totalL = Bb * Nn;               // labels
  const int stride = gridDim.x * blockDim.x;
  float4* out4 = reinterpret_cast<float4*>(out + OFF_TGT);
  const float4* obs4 = reinterpret_cast<const float4*>(obs);
  for (int idx = blockIdx.x * blockDim.x + threadIdx.x;
       idx < total4 + totalL; idx += stride) {
    if (idx < total4) {
      const int b = idx / (Nn * 8);
      const int r = idx - b * (Nn * 8);
      const int n = r >> 3;
      const int c4 = r & 7;
      out4[idx] = obs4[((long)b * Tt + n + WL - 1) * 8 + c4];
    } else {
      const int j = idx - total4;
      const int b = j / Nn;
      const int n = j - b * Nn;
      out[OFF_LAB + j] = (float)tlab[(long)b * Tt + n + WL - 1];
    }
  }
}

// ---------------- encoder: priors = MLP3(win) ----------------
// block = (b, 64-wide n tile), 256 threads = 16 j-groups x 16 n-groups, 4x4 reg tile
__global__ __launch_bounds__(256) void enc_kernel(
    const float* __restrict__ obs, const float* __restrict__ act,
    const float* __restrict__ W1, const float* __restrict__ b1,
    const float* __restrict__ W2, const float* __restrict__ b2,
    const float* __restrict__ W3, const float* __restrict__ b3,
    float* __restrict__ out) {
  __shared__ float sA[73][41];
  __shared__ float sH1[64][65];
  __shared__ float sH2[64][65];
  const int b = blockIdx.x >> 3;
  const int n0 = (blockIdx.x & 7) << 6;
  const int tid = threadIdx.x;

  // stage oa[b, n0 .. n0+72, 0..39] (clamped)
  for (int e = tid; e < 73 * CH; e += 256) {
    const int row = e / CH;
    const int c = e - row * CH;
    int t = n0 + row;
    t = t < Tt ? t : Tt - 1;
    const float v = (c < OD) ? obs[((long)b * Tt + t) * OD + c]
                             : act[((long)b * Tt + t) * AD + (c - OD)];
    sA[row][c] = v;
  }
  __syncthreads();

  const int tj = tid & 15;   // j = tj*4 .. tj*4+3
  const int tn = tid >> 4;   // n = tn*4 .. tn*4+3

  // layer 1: K = 400, k = c*10 + w, x[k] = sA[n+w][c]
  float acc[4][4] = {};
  for (int w = 0; w < WL; ++w) {
    const float* xc = &sA[tn * 4 + w][0];   // rows dn -> +dn*41
    const float* wp = W1 + w * 64 + tj * 4;
#pragma unroll 2
    for (int c = 0; c < CH; ++c) {
      const float4 wv = *reinterpret_cast<const float4*>(wp + c * 640);
#pragma unroll
      for (int dn = 0; dn < 4; ++dn) {
        const float xv = xc[dn * 41 + c];
        acc[dn][0] = fmaf(xv, wv.x, acc[dn][0]);
        acc[dn][1] = fmaf(xv, wv.y, acc[dn][1]);
        acc[dn][2] = fmaf(xv, wv.z, acc[dn][2]);
        acc[dn][3] = fmaf(xv, wv.w, acc[dn][3]);
      }
    }
  }
  {
    const float4 bs = *reinterpret_cast<const float4*>(b1 + tj * 4);
#pragma unroll
    for (int dn = 0; dn < 4; ++dn) {
      sH1[tn * 4 + dn][tj * 4 + 0] = fmaxf(acc[dn][0] + bs.x, 0.0f);
      sH1[tn * 4 + dn][tj * 4 + 1] = fmaxf(acc[dn][1] + bs.y, 0.0f);
      sH1[tn * 4 + dn][tj * 4 + 2] = fmaxf(acc[dn][2] + bs.z, 0.0f);
      sH1[tn * 4 + dn][tj * 4 + 3] = fmaxf(acc[dn][3] + bs.w, 0.0f);
    }
  }
  __syncthreads();

  // layer 2: 64x64
  float acc2[4][4] = {};
#pragma unroll 2
  for (int k = 0; k < 64; ++k) {
    const float4 wv = *reinterpret_cast<const float4*>(W2 + k * 64 + tj * 4);
#pragma unroll
    for (int dn = 0; dn < 4; ++dn) {
      const float xv = sH1[tn * 4 + dn][k];
      acc2[dn][0] = fmaf(xv, wv.x, acc2[dn][0]);
      acc2[dn][1] = fmaf(xv, wv.y, acc2[dn][1]);
      acc2[dn][2] = fmaf(xv, wv.z, acc2[dn][2]);
      acc2[dn][3] = fmaf(xv, wv.w, acc2[dn][3]);
    }
  }
  {
    const float4 bs = *reinterpret_cast<const float4*>(b2 + tj * 4);
#pragma unroll
    for (int dn = 0; dn < 4; ++dn) {
      sH2[tn * 4 + dn][tj * 4 + 0] = fmaxf(acc2[dn][0] + bs.x, 0.0f);
      sH2[tn * 4 + dn][tj * 4 + 1] = fmaxf(acc2[dn][1] + bs.y, 0.0f);
      sH2[tn * 4 + dn][tj * 4 + 2] = fmaxf(acc2[dn][2] + bs.z, 0.0f);
      sH2[tn * 4 + dn][tj * 4 + 3] = fmaxf(acc2[dn][3] + bs.w, 0.0f);
    }
  }
  __syncthreads();

  // layer 3: 64 n x 2 outputs
  if (tid < 128) {
    const int n = tid >> 1;
    const int o = tid & 1;
    float a = b3[o];
#pragma unroll 4
    for (int k = 0; k < 64; ++k) a = fmaf(sH2[n][k], W3[k * 2 + o], a);
    const int nn = n0 + n;
    if (nn < Nn) out[OFF_PRIORS + ((long)b * Nn + nn) * 2 + o] = a;
  }
}

// ---------------- sequential GRU + post-MLP scan ----------------
// 16 lanes per batch element; 32 blocks x 256 threads = 512 groups
__global__ __launch_bounds__(256) void scan_kernel(
    const float* __restrict__ act, const int* __restrict__ mask,
    const float* __restrict__ Wih, const float* __restrict__ Whh,
    const float* __restrict__ bih, const float* __restrict__ bhh,
    const float* __restrict__ pW1, const float* __restrict__ pb1,
    const float* __restrict__ pW2, const float* __restrict__ pb2,
    const float* __restrict__ pW3, const float* __restrict__ pb3,
    float* __restrict__ out) {
  const int tid = threadIdx.x;
  const int lane = tid & 15;
  const int g = (blockIdx.x * 256 + tid) >> 4;   // batch element

  // per-lane weights
  float wih[10];
  float bihq = 0.f, whh0 = 0.f, whh1 = 0.f, bhhq = 0.f;
  if (lane < 6) {
#pragma unroll
    for (int i = 0; i < 10; ++i) wih[i] = Wih[i * 6 + lane];
    bihq = bih[lane];
    whh0 = Whh[lane];
    whh1 = Whh[6 + lane];
    bhhq = bhh[lane];
  } else {
#pragma unroll
    for (int i = 0; i < 10; ++i) wih[i] = 0.f;
  }
  const float w1c0 = pW1[lane], w1c1 = pW1[16 + lane], b1v = pb1[lane];
  float w2[16];
#pragma unroll
  for (int k = 0; k < 16; ++k) w2[k] = pW2[k * 16 + lane];
  const float b2v = pb2[lane];
  const float w3a = pW3[lane * 2], w3b = pW3[lane * 2 + 1];
  const float b3a = pb3[0], b3b = pb3[1];

  const float* priors = out + OFF_PRIORS;
  float* posts = out + OFF_POSTS;
  float* xtraj = out + OFF_XTRAJ;
  const long pbase = (long)g * Nn;
  const float* aptr = act + ((long)g * Tt + WL - 1) * 8;

  float2 s0v = *reinterpret_cast<const float2*>(priors + pbase * 2);
  float x0p = 0.f, x1p = 0.f;
  float s0p = s0v.x, s1p = s0v.y;
  if (lane == 0)
    *reinterpret_cast<float2*>(xtraj + pbase * 2) = make_float2(0.f, 0.f);
  if (lane == 1)
    *reinterpret_cast<float2*>(posts + pbase * 2) = make_float2(s0p, s1p);

  // prefetch t = 0
  float2 prn = s0v;
  float4 an0 = *reinterpret_cast<const float4*>(aptr);
  float4 an1 = *reinterpret_cast<const float4*>(aptr + 4);
  int mn = mask[pbase];

  for (int t = 0; t < Nn - 1; ++t) {
    const float2 pr = prn;
    const float4 a0 = an0, a1 = an1;
    const int m = mn;
    // prefetch t+1 (all addresses valid: t+1 <= 502)
    prn = *reinterpret_cast<const float2*>(priors + (pbase + t + 1) * 2);
    an0 = *reinterpret_cast<const float4*>(aptr + (t + 1) * 8);
    an1 = *reinterpret_cast<const float4*>(aptr + (t + 1) * 8 + 4);
    mn = mask[pbase + t + 1];

    const float st0 = m ? pr.x : s0p;
    const float st1 = m ? pr.y : s1p;
    float gi = bihq;
    gi = fmaf(a0.x, wih[0], gi); gi = fmaf(a0.y, wih[1], gi);
    gi = fmaf(a0.z, wih[2], gi); gi = fmaf(a0.w, wih[3], gi);
    gi = fmaf(a1.x, wih[4], gi); gi = fmaf(a1.y, wih[5], gi);
    gi = fmaf(a1.z, wih[6], gi); gi = fmaf(a1.w, wih[7], gi);
    gi = fmaf(st0, wih[8], gi);  gi = fmaf(st1, wih[9], gi);
    const float gh = fmaf(x1p, whh1, fmaf(x0p, whh0, bhhq));

    float gi_[6], gh_[6];
#pragma unroll
    for (int q = 0; q < 6; ++q) {
      gi_[q] = __shfl(gi, q, 16);
      gh_[q] = __shfl(gh, q, 16);
    }
    const float r0 = sigmoidf_(gi_[0] + gh_[0]);
    const float r1 = sigmoidf_(gi_[1] + gh_[1]);
    const float z0 = sigmoidf_(gi_[2] + gh_[2]);
    const float z1 = sigmoidf_(gi_[3] + gh_[3]);
    const float nn0 = tanh_(fmaf(r0, gh_[4], gi_[4]));
    const float nn1 = tanh_(fmaf(r1, gh_[5], gi_[5]));
    const float xn0 = (1.0f - z0) * nn0 + z0 * x0p;
    const float xn1 = (1.0f - z1) * nn1 + z1 * x1p;

    // post MLP: 2 -> 16 -> 16 -> 2 across the 16 lanes
    const float h1 = fmaxf(fmaf(xn1, w1c1, fmaf(xn0, w1c0, b1v)), 0.0f);
    float accp = b2v;
#pragma unroll
    for (int k = 0; k < 16; ++k) accp = fmaf(__shfl(h1, k, 16), w2[k], accp);
    const float h2 = fmaxf(accp, 0.0f);
    float p0 = h2 * w3a, p1 = h2 * w3b;
    p0 += __shfl_xor(p0, 8, 16); p1 += __shfl_xor(p1, 8, 16);
    p0 += __shfl_xor(p0, 4, 16); p1 += __shfl_xor(p1, 4, 16);
    p0 += __shfl_xor(p0, 2, 16); p1 += __shfl_xor(p1, 2, 16);
    p0 += __shfl_xor(p0, 1, 16); p1 += __shfl_xor(p1, 1, 16);
    const float sn0 = p0 + b3a, sn1 = p1 + b3b;

    if (lane == 0)
      *reinterpret_cast<float2*>(xtraj + (pbase + t + 1) * 2) = make_float2(xn0, xn1);
    if (lane == 1)
      *reinterpret_cast<float2*>(posts + (pbase + t + 1) * 2) = make_float2(sn0, sn1);
    x0p = xn0; x1p = xn1; s0p = sn0; s1p = sn1;
  }
}

// ---------------- decoder: post_obs_pred = MLP3([posts, action_traj]) ----------------
__global__ __launch_bounds__(256) void dec_kernel(
    const float* __restrict__ act,
    const float* __restrict__ W1, const float* __restrict__ b1,
    const float* __restrict__ W2, const float* __restrict__ b2,
    const float* __restrict__ W3, const float* __restrict__ b3,
    float* __restrict__ out) {
  __shared__ float sD[64][12];
  __shared__ float sH1[64][65];
  __shared__ float sH2[64][65];
  const int b = blockIdx.x >> 3;
  const int n0 = (blockIdx.x & 7) << 6;
  const int tid = threadIdx.x;
  const float* posts = out + OFF_POSTS;

  for (int e = tid; e < 64 * 10; e += 256) {
    const int row = e / 10;
    const int k = e - row * 10;
    int nn = n0 + row;
    nn = nn < Nn ? nn : Nn - 1;
    const float v = (k < 2) ? posts[((long)b * Nn + nn) * 2 + k]
                            : act[((long)b * Tt + nn + WL - 1) * AD + (k - 2)];
    sD[row][k] = v;
  }
  __syncthreads();

  const int tj = tid & 15;
  const int tn = tid >> 4;

  float acc[4][4] = {};
#pragma unroll
  for (int k = 0; k < 10; ++k) {
    const float4 wv = *reinterpret_cast<const float4*>(W1 + k * 64 + tj * 4);
#pragma unroll
    for (int dn = 0; dn < 4; ++dn) {
      const float xv = sD[tn * 4 + dn][k];
      acc[dn][0] = fmaf(xv, wv.x, acc[dn][0]);
      acc[dn][1] = fmaf(xv, wv.y, acc[dn][1]);
      acc[dn][2] = fmaf(xv, wv.z, acc[dn][2]);
      acc[dn][3] = fmaf(xv, wv.w, acc[dn][3]);
    }
  }
  {
    const float4 bs = *reinterpret_cast<const float4*>(b1 + tj * 4);
#pragma unroll
    for (int dn = 0; dn < 4; ++dn) {
      sH1[tn * 4 + dn][tj * 4 + 0] = fmaxf(acc[dn][0] + bs.x, 0.0f);
      sH1[tn * 4 + dn][tj * 4 + 1] = fmaxf(acc[dn][1] + bs.y, 0.0f);
      sH1[tn * 4 + dn][tj * 4 + 2] = fmaxf(acc[dn][2] + bs.z, 0.0f);
      sH1[tn * 4 + dn][tj * 4 + 3] = fmaxf(acc[dn][3] + bs.w, 0.0f);
    }
  }
  __syncthreads();

  float acc2[4][4] = {};
#pragma unroll 2
  for (int k = 0; k < 64; ++k) {
    const float4 wv = *reinterpret_cast<const float4*>(W2 + k * 64 + tj * 4);
#pragma unroll
    for (int dn = 0; dn < 4; ++dn) {
      const float xv = sH1[tn * 4 + dn][k];
      acc2[dn][0] = fmaf(xv, wv.x, acc2[dn][0]);
      acc2[dn][1] = fmaf(xv, wv.y, acc2[dn][1]);
      acc2[dn][2] = fmaf(xv, wv.z, acc2[dn][2]);
      acc2[dn][3] = fmaf(xv, wv.w, acc2[dn][3]);
    }
  }
  {
    const float4 bs = *reinterpret_cast<const float4*>(b2 + tj * 4);
#pragma unroll
    for (int dn = 0; dn < 4; ++dn) {
      sH2[tn * 4 + dn][tj * 4 + 0] = fmaxf(acc2[dn][0] + bs.x, 0.0f);
      sH2[tn * 4 + dn][tj * 4 + 1] = fmaxf(acc2[dn][1] + bs.y, 0.0f);
      sH2[tn * 4 + dn][tj * 4 + 2] = fmaxf(acc2[dn][2] + bs.z, 0.0f);
      sH2[tn * 4 + dn][tj * 4 + 3] = fmaxf(acc2[dn][3] + bs.w, 0.0f);
    }
  }
  __syncthreads();

  // layer 3: 64 n x 32 o
  {
    const int o = tid & 31;
    const int ng = tid >> 5;   // 8 groups of 8 rows
    float a[8];
#pragma unroll
    for (int r = 0; r < 8; ++r) a[r] = b3[o];
#pragma unroll 2
    for (int k = 0; k < 64; ++k) {
      const float wv = W3[k * 32 + o];
#pragma unroll
      for (int r = 0; r < 8; ++r)
        a[r] = fmaf(sH2[ng * 8 + r][k], wv, a[r]);
    }
#pragma unroll
    for (int r = 0; r < 8; ++r) {
      const int nn = n0 + ng * 8 + r;
      if (nn < Nn) out[OFF_POST + ((long)b * Nn + nn) * 32 + o] = a[r];
    }
  }
}

}  // namespace

extern "C" void kernel_launch(void* const* d_in, const int* in_sizes, int n_in,
                              void* d_out, int out_size, void* d_ws, size_t ws_size,
                              hipStream_t stream) {
  const float* obs    = (const float*)d_in[0];
  const float* action = (const float*)d_in[1];
  const int* t_label  = (const int*)d_in[2];
  const int* mask     = (const int*)d_in[3];
  const float* enc_W1 = (const float*)d_in[4];
  const float* enc_b1 = (const float*)d_in[5];
  const float* enc_W2 = (const float*)d_in[6];
  const float* enc_b2 = (const float*)d_in[7];
  const float* enc_W3 = (const float*)d_in[8];
  const float* enc_b3 = (const float*)d_in[9];
  const float* gru_Wih = (const float*)d_in[10];
  const float* gru_Whh = (const float*)d_in[11];
  const float* gru_bih = (const float*)d_in[12];
  const float* gru_bhh = (const float*)d_in[13];
  const float* post_W1 = (const float*)d_in[14];
  const float* post_b1 = (const float*)d_in[15];
  const float* post_W2 = (const float*)d_in[16];
  const float* post_b2 = (const float*)d_in[17];
  const float* post_W3 = (const float*)d_in[18];
  const float* post_b3 = (const float*)d_in[19];
  const float* dec_W1 = (const float*)d_in[20];
  const float* dec_b1 = (const float*)d_in[21];
  const float* dec_W2 = (const float*)d_in[22];
  const float* dec_b2 = (const float*)d_in[23];
  const float* dec_W3 = (const float*)d_in[24];
  const float* dec_b3 = (const float*)d_in[25];
  float* out = (float*)d_out;

  enc_kernel<<<Bb * 8, 256, 0, stream>>>(obs, action, enc_W1, enc_b1, enc_W2,
                                         enc_b2, enc_W3, enc_b3, out);
  scan_kernel<<<32, 256, 0, stream>>>(action, mask, gru_Wih, gru_Whh, gru_bih,
                                      gru_bhh, post_W1, post_b1, post_W2,
                                      post_b2, post_W3, post_b3, out);
  dec_kernel<<<Bb * 8, 256, 0, stream>>>(action, dec_W1, dec_b1, dec_W2, dec_b2,
                                         dec_W3, dec_b3, out);
  copy_kernel<<<2048, 256, 0, stream>>>(obs, t_label, out);
}

// Round 2
// 701.425 us; speedup vs baseline: 1.1615x; 1.1615x over previous
//
#include <hip/hip_runtime.h>
#include <hip/hip_bf16.h>

namespace {

constexpr int Bb = 512;
constexpr int Tt = 512;
constexpr int OD = 32;
constexpr int AD = 8;
constexpr int WL = 10;
constexpr int Nn = Tt - WL + 1;   // 503
constexpr int CH = OD + AD;       // 40

constexpr long SZ_PO = (long)Bb * Nn * 32;   // 8,241,152
constexpr long SZ_PR = (long)Bb * Nn * 2;    // 515,072
constexpr long OFF_POST   = 0;
constexpr long OFF_PRIORS = SZ_PO;
constexpr long OFF_POSTS  = OFF_PRIORS + SZ_PR;
constexpr long OFF_XTRAJ  = OFF_POSTS + SZ_PR;
constexpr long OFF_TGT    = OFF_XTRAJ + SZ_PR;
constexpr long OFF_LAB    = OFF_TGT + SZ_PO;

__device__ __forceinline__ float sigmoidf_(float x) {
  return 1.0f / (1.0f + __expf(-x));
}
__device__ __forceinline__ float tanh_(float x) {
  return 1.0f - 2.0f / (__expf(2.0f * x) + 1.0f);
}

// DPP add: x + dpp_perm(x). CTRL compile-time.
template <int CTRL>
__device__ __forceinline__ float dpp_add(float x) {
  int y = __builtin_amdgcn_update_dpp(0, __float_as_int(x), CTRL, 0xf, 0xf, false);
  return x + __int_as_float(y);
}
// 16-lane all-reduce sum, bit-identical on all lanes (commutative butterfly).
__device__ __forceinline__ float row16_allsum(float x) {
  x = dpp_add<0xB1>(x);   // quad_perm [1,0,3,2]  (xor 1)
  x = dpp_add<0x4E>(x);   // quad_perm [2,3,0,1]  (xor 2)
  x = dpp_add<0x141>(x);  // row_half_mirror      (other quad within 8)
  x = dpp_add<0x140>(x);  // row_mirror           (other 8 within 16)
  return x;
}

// ---------------- copies: target_obs_traj + labels ----------------
__global__ void copy_kernel(const float* __restrict__ obs,
                            const int* __restrict__ tlab,
                            float* __restrict__ out) {
  const int total4 = (int)(SZ_PO / 4);
  const int totalL = Bb * Nn;
  const int stride = gridDim.x * blockDim.x;
  float4* out4 = reinterpret_cast<float4*>(out + OFF_TGT);
  const float4* obs4 = reinterpret_cast<const float4*>(obs);
  for (int idx = blockIdx.x * blockDim.x + threadIdx.x;
       idx < total4 + totalL; idx += stride) {
    if (idx < total4) {
      const int b = idx / (Nn * 8);
      const int r = idx - b * (Nn * 8);
      const int n = r >> 3;
      const int c4 = r & 7;
      out4[idx] = obs4[((long)b * Tt + n + WL - 1) * 8 + c4];
    } else {
      const int j = idx - total4;
      const int b = j / Nn;
      const int n = j - b * Nn;
      out[OFF_LAB + j] = (float)tlab[(long)b * Tt + n + WL - 1];
    }
  }
}

// ---------------- encoder: priors = MLP3(win) ----------------
__global__ __launch_bounds__(256) void enc_kernel(
    const float* __restrict__ obs, const float* __restrict__ act,
    const float* __restrict__ W1, const float* __restrict__ b1,
    const float* __restrict__ W2, const float* __restrict__ b2,
    const float* __restrict__ W3, const float* __restrict__ b3,
    float* __restrict__ out) {
  __shared__ float sA[73][41];
  __shared__ float sH1[64][65];
  __shared__ float sH2[64][65];
  const int b = blockIdx.x >> 3;
  const int n0 = (blockIdx.x & 7) << 6;
  const int tid = threadIdx.x;

  for (int e = tid; e < 73 * CH; e += 256) {
    const int row = e / CH;
    const int c = e - row * CH;
    int t = n0 + row;
    t = t < Tt ? t : Tt - 1;
    const float v = (c < OD) ? obs[((long)b * Tt + t) * OD + c]
                             : act[((long)b * Tt + t) * AD + (c - OD)];
    sA[row][c] = v;
  }
  __syncthreads();

  const int tj = tid & 15;
  const int tn = tid >> 4;

  float acc[4][4] = {};
  for (int w = 0; w < WL; ++w) {
    const float* xc = &sA[tn * 4 + w][0];
    const float* wp = W1 + w * 64 + tj * 4;
#pragma unroll 2
    for (int c = 0; c < CH; ++c) {
      const float4 wv = *reinterpret_cast<const float4*>(wp + c * 640);
#pragma unroll
      for (int dn = 0; dn < 4; ++dn) {
        const float xv = xc[dn * 41 + c];
        acc[dn][0] = fmaf(xv, wv.x, acc[dn][0]);
        acc[dn][1] = fmaf(xv, wv.y, acc[dn][1]);
        acc[dn][2] = fmaf(xv, wv.z, acc[dn][2]);
        acc[dn][3] = fmaf(xv, wv.w, acc[dn][3]);
      }
    }
  }
  {
    const float4 bs = *reinterpret_cast<const float4*>(b1 + tj * 4);
#pragma unroll
    for (int dn = 0; dn < 4; ++dn) {
      sH1[tn * 4 + dn][tj * 4 + 0] = fmaxf(acc[dn][0] + bs.x, 0.0f);
      sH1[tn * 4 + dn][tj * 4 + 1] = fmaxf(acc[dn][1] + bs.y, 0.0f);
      sH1[tn * 4 + dn][tj * 4 + 2] = fmaxf(acc[dn][2] + bs.z, 0.0f);
      sH1[tn * 4 + dn][tj * 4 + 3] = fmaxf(acc[dn][3] + bs.w, 0.0f);
    }
  }
  __syncthreads();

  float acc2[4][4] = {};
#pragma unroll 2
  for (int k = 0; k < 64; ++k) {
    const float4 wv = *reinterpret_cast<const float4*>(W2 + k * 64 + tj * 4);
#pragma unroll
    for (int dn = 0; dn < 4; ++dn) {
      const float xv = sH1[tn * 4 + dn][k];
      acc2[dn][0] = fmaf(xv, wv.x, acc2[dn][0]);
      acc2[dn][1] = fmaf(xv, wv.y, acc2[dn][1]);
      acc2[dn][2] = fmaf(xv, wv.z, acc2[dn][2]);
      acc2[dn][3] = fmaf(xv, wv.w, acc2[dn][3]);
    }
  }
  {
    const float4 bs = *reinterpret_cast<const float4*>(b2 + tj * 4);
#pragma unroll
    for (int dn = 0; dn < 4; ++dn) {
      sH2[tn * 4 + dn][tj * 4 + 0] = fmaxf(acc2[dn][0] + bs.x, 0.0f);
      sH2[tn * 4 + dn][tj * 4 + 1] = fmaxf(acc2[dn][1] + bs.y, 0.0f);
      sH2[tn * 4 + dn][tj * 4 + 2] = fmaxf(acc2[dn][2] + bs.z, 0.0f);
      sH2[tn * 4 + dn][tj * 4 + 3] = fmaxf(acc2[dn][3] + bs.w, 0.0f);
    }
  }
  __syncthreads();

  if (tid < 128) {
    const int n = tid >> 1;
    const int o = tid & 1;
    float a = b3[o];
#pragma unroll 4
    for (int k = 0; k < 64; ++k) a = fmaf(sH2[n][k], W3[k * 2 + o], a);
    const int nn = n0 + n;
    if (nn < Nn) out[OFF_PRIORS + ((long)b * Nn + nn) * 2 + o] = a;
  }
}

// ---------------- gia precompute: action part of GRU input gates ----------------
// gia[g][t][q] = bih[q] + sum_i a_t[i] * Wih[i][q], padded to 8 floats
__global__ __launch_bounds__(256) void gia_kernel(const float* __restrict__ act,
                                                  const float* __restrict__ Wih,
                                                  const float* __restrict__ bih,
                                                  float* __restrict__ gia) {
  const int idx = blockIdx.x * 256 + threadIdx.x;
  const int total = Bb * (Nn - 1);
  if (idx >= total) return;
  const int g = idx / (Nn - 1);
  const int t = idx - g * (Nn - 1);
  const float* a = act + ((long)g * Tt + WL - 1 + t) * AD;
  const float4 a0 = *reinterpret_cast<const float4*>(a);
  const float4 a1 = *reinterpret_cast<const float4*>(a + 4);
  float r[8];
#pragma unroll
  for (int q = 0; q < 6; ++q) {
    float acc = bih[q];
    acc = fmaf(a0.x, Wih[0 * 6 + q], acc);
    acc = fmaf(a0.y, Wih[1 * 6 + q], acc);
    acc = fmaf(a0.z, Wih[2 * 6 + q], acc);
    acc = fmaf(a0.w, Wih[3 * 6 + q], acc);
    acc = fmaf(a1.x, Wih[4 * 6 + q], acc);
    acc = fmaf(a1.y, Wih[5 * 6 + q], acc);
    acc = fmaf(a1.z, Wih[6 * 6 + q], acc);
    acc = fmaf(a1.w, Wih[7 * 6 + q], acc);
    r[q] = acc;
  }
  r[6] = 0.f;
  r[7] = 0.f;
  float4* o = reinterpret_cast<float4*>(gia + (long)idx * 8);
  o[0] = make_float4(r[0], r[1], r[2], r[3]);
  o[1] = make_float4(r[4], r[5], r[6], r[7]);
}

// ---------------- sequential GRU + post-MLP scan v2 ----------------
// 16 lanes per batch element; 128 blocks x 64 threads -> 1 wave/CU.
// All gates computed redundantly per-lane (no broadcast shfls); only h1
// all-gather uses shfl (independent); final reduce via full-rate DPP.
template <bool USE_GIA>
__global__ __launch_bounds__(64) void scan_kernel(
    const float* __restrict__ act, const int* __restrict__ mask,
    const float* __restrict__ Wih, const float* __restrict__ Whh,
    const float* __restrict__ bih, const float* __restrict__ bhh,
    const float* __restrict__ pW1, const float* __restrict__ pb1,
    const float* __restrict__ pW2, const float* __restrict__ pb2,
    const float* __restrict__ pW3, const float* __restrict__ pb3,
    const float* __restrict__ gia,
    float* __restrict__ out) {
  const int tid = threadIdx.x;
  const int lane = tid & 15;
  const int g = (blockIdx.x * 64 + tid) >> 4;

  // uniform weights (scalar-register resident)
  float wih8[6], wih9[6], whh0[6], whh1[6], bhhv[6];
#pragma unroll
  for (int q = 0; q < 6; ++q) {
    wih8[q] = Wih[8 * 6 + q];
    wih9[q] = Wih[9 * 6 + q];
    whh0[q] = Whh[q];
    whh1[q] = Whh[6 + q];
    bhhv[q] = bhh[q];
  }
  float wihA[8][6];
  float bihv[6];
  if constexpr (!USE_GIA) {
#pragma unroll
    for (int i = 0; i < 8; ++i)
#pragma unroll
      for (int q = 0; q < 6; ++q) wihA[i][q] = Wih[i * 6 + q];
#pragma unroll
    for (int q = 0; q < 6; ++q) bihv[q] = bih[q];
  }

  // per-lane weights (lane = hidden unit j)
  const float w1c0 = pW1[lane], w1c1 = pW1[16 + lane], b1v = pb1[lane];
  float w2c[16];
#pragma unroll
  for (int k = 0; k < 16; ++k) w2c[k] = pW2[k * 16 + lane];
  const float b2v = pb2[lane];
  const float w3a = pW3[lane * 2], w3b = pW3[lane * 2 + 1];
  const float b3a = pb3[0], b3b = pb3[1];

  const float* priors = out + OFF_PRIORS;
  float* posts = out + OFF_POSTS;
  float* xtraj = out + OFF_XTRAJ;
  const long pbase = (long)g * Nn;
  const float* giap = gia + (long)g * (Nn - 1) * 8;
  const float* aptr = act + ((long)g * Tt + WL - 1) * 8;

  const float2 s0v = *reinterpret_cast<const float2*>(priors + pbase * 2);
  float x0p = 0.f, x1p = 0.f;
  float s0p = s0v.x, s1p = s0v.y;
  if (lane == 0)
    *reinterpret_cast<float2*>(xtraj + pbase * 2) = make_float2(0.f, 0.f);
  if (lane == 1)
    *reinterpret_cast<float2*>(posts + pbase * 2) = make_float2(s0p, s1p);

  // prefetch t = 0
  float4 gf0, gf1, an0, an1;
  if constexpr (USE_GIA) {
    gf0 = *reinterpret_cast<const float4*>(giap);
    gf1 = *reinterpret_cast<const float4*>(giap + 4);
  } else {
    an0 = *reinterpret_cast<const float4*>(aptr);
    an1 = *reinterpret_cast<const float4*>(aptr + 4);
  }
  float2 prn = s0v;
  int mn = mask[pbase];

  for (int t = 0; t < Nn - 1; ++t) {
    const float4 g0 = gf0, g1 = gf1, a0 = an0, a1 = an1;
    const float2 pr = prn;
    const int m = mn;
    // prefetch t+1
    const int tn1 = (t + 1 < Nn - 1) ? t + 1 : Nn - 2;
    if constexpr (USE_GIA) {
      gf0 = *reinterpret_cast<const float4*>(giap + (long)tn1 * 8);
      gf1 = *reinterpret_cast<const float4*>(giap + (long)tn1 * 8 + 4);
    } else {
      an0 = *reinterpret_cast<const float4*>(aptr + (long)tn1 * 8);
      an1 = *reinterpret_cast<const float4*>(aptr + (long)tn1 * 8 + 4);
    }
    prn = *reinterpret_cast<const float2*>(priors + (pbase + t + 1) * 2);
    mn = mask[pbase + t + 1];

    const float st0 = m ? pr.x : s0p;
    const float st1 = m ? pr.y : s1p;

    float giq[6], ghq[6];
    float gbase[6];
    if constexpr (USE_GIA) {
      gbase[0] = g0.x; gbase[1] = g0.y; gbase[2] = g0.z;
      gbase[3] = g0.w; gbase[4] = g1.x; gbase[5] = g1.y;
    } else {
#pragma unroll
      for (int q = 0; q < 6; ++q) {
        float acc = bihv[q];
        acc = fmaf(a0.x, wihA[0][q], acc);
        acc = fmaf(a0.y, wihA[1][q], acc);
        acc = fmaf(a0.z, wihA[2][q], acc);
        acc = fmaf(a0.w, wihA[3][q], acc);
        acc = fmaf(a1.x, wihA[4][q], acc);
        acc = fmaf(a1.y, wihA[5][q], acc);
        acc = fmaf(a1.z, wihA[6][q], acc);
        acc = fmaf(a1.w, wihA[7][q], acc);
        gbase[q] = acc;
      }
    }
#pragma unroll
    for (int q = 0; q < 6; ++q) {
      giq[q] = fmaf(st1, wih9[q], fmaf(st0, wih8[q], gbase[q]));
      ghq[q] = fmaf(x1p, whh1[q], fmaf(x0p, whh0[q], bhhv[q]));
    }
    const float r0 = sigmoidf_(giq[0] + ghq[0]);
    const float r1 = sigmoidf_(giq[1] + ghq[1]);
    const float z0 = sigmoidf_(giq[2] + ghq[2]);
    const float z1 = sigmoidf_(giq[3] + ghq[3]);
    const float nn0 = tanh_(fmaf(r0, ghq[4], giq[4]));
    const float nn1 = tanh_(fmaf(r1, ghq[5], giq[5]));
    const float xn0 = fmaf(z0, x0p - nn0, nn0);
    const float xn1 = fmaf(z1, x1p - nn1, nn1);

    // post MLP: h1[lane] -> gather -> h2[lane] -> DPP all-reduce
    const float h1 = fmaxf(fmaf(xn1, w1c1, fmaf(xn0, w1c0, b1v)), 0.0f);
    float ha[16];
#pragma unroll
    for (int k = 0; k < 16; ++k) ha[k] = __shfl(h1, k, 16);
    float q0 = fmaf(ha[0], w2c[0], b2v);
    q0 = fmaf(ha[1], w2c[1], q0);
    q0 = fmaf(ha[2], w2c[2], q0);
    q0 = fmaf(ha[3], w2c[3], q0);
    float q1 = ha[4] * w2c[4];
    q1 = fmaf(ha[5], w2c[5], q1);
    q1 = fmaf(ha[6], w2c[6], q1);
    q1 = fmaf(ha[7], w2c[7], q1);
    float q2 = ha[8] * w2c[8];
    q2 = fmaf(ha[9], w2c[9], q2);
    q2 = fmaf(ha[10], w2c[10], q2);
    q2 = fmaf(ha[11], w2c[11], q2);
    float q3 = ha[12] * w2c[12];
    q3 = fmaf(ha[13], w2c[13], q3);
    q3 = fmaf(ha[14], w2c[14], q3);
    q3 = fmaf(ha[15], w2c[15], q3);
    const float h2 = fmaxf((q0 + q1) + (q2 + q3), 0.0f);

    float p0 = h2 * w3a;
    float p1 = h2 * w3b;
    p0 = row16_allsum(p0);
    p1 = row16_allsum(p1);
    const float sn0 = p0 + b3a;
    const float sn1 = p1 + b3b;

    if (lane == 0)
      *reinterpret_cast<float2*>(xtraj + (pbase + t + 1) * 2) =
          make_float2(xn0, xn1);
    if (lane == 1)
      *reinterpret_cast<float2*>(posts + (pbase + t + 1) * 2) =
          make_float2(sn0, sn1);
    x0p = xn0; x1p = xn1; s0p = sn0; s1p = sn1;
  }
}

// ---------------- decoder ----------------
__global__ __launch_bounds__(256) void dec_kernel(
    const float* __restrict__ act,
    const float* __restrict__ W1, const float* __restrict__ b1,
    const float* __restrict__ W2, const float* __restrict__ b2,
    const float* __restrict__ W3, const float* __restrict__ b3,
    float* __restrict__ out) {
  __shared__ float sD[64][12];
  __shared__ float sH1[64][65];
  __shared__ float sH2[64][65];
  const int b = blockIdx.x >> 3;
  const int n0 = (blockIdx.x & 7) << 6;
  const int tid = threadIdx.x;
  const float* posts = out + OFF_POSTS;

  for (int e = tid; e < 64 * 10; e += 256) {
    const int row = e / 10;
    const int k = e - row * 10;
    int nn = n0 + row;
    nn = nn < Nn ? nn : Nn - 1;
    const float v = (k < 2) ? posts[((long)b * Nn + nn) * 2 + k]
                            : act[((long)b * Tt + nn + WL - 1) * AD + (k - 2)];
    sD[row][k] = v;
  }
  __syncthreads();

  const int tj = tid & 15;
  const int tn = tid >> 4;

  float acc[4][4] = {};
#pragma unroll
  for (int k = 0; k < 10; ++k) {
    const float4 wv = *reinterpret_cast<const float4*>(W1 + k * 64 + tj * 4);
#pragma unroll
    for (int dn = 0; dn < 4; ++dn) {
      const float xv = sD[tn * 4 + dn][k];
      acc[dn][0] = fmaf(xv, wv.x, acc[dn][0]);
      acc[dn][1] = fmaf(xv, wv.y, acc[dn][1]);
      acc[dn][2] = fmaf(xv, wv.z, acc[dn][2]);
      acc[dn][3] = fmaf(xv, wv.w, acc[dn][3]);
    }
  }
  {
    const float4 bs = *reinterpret_cast<const float4*>(b1 + tj * 4);
#pragma unroll
    for (int dn = 0; dn < 4; ++dn) {
      sH1[tn * 4 + dn][tj * 4 + 0] = fmaxf(acc[dn][0] + bs.x, 0.0f);
      sH1[tn * 4 + dn][tj * 4 + 1] = fmaxf(acc[dn][1] + bs.y, 0.0f);
      sH1[tn * 4 + dn][tj * 4 + 2] = fmaxf(acc[dn][2] + bs.z, 0.0f);
      sH1[tn * 4 + dn][tj * 4 + 3] = fmaxf(acc[dn][3] + bs.w, 0.0f);
    }
  }
  __syncthreads();

  float acc2[4][4] = {};
#pragma unroll 2
  for (int k = 0; k < 64; ++k) {
    const float4 wv = *reinterpret_cast<const float4*>(W2 + k * 64 + tj * 4);
#pragma unroll
    for (int dn = 0; dn < 4; ++dn) {
      const float xv = sH1[tn * 4 + dn][k];
      acc2[dn][0] = fmaf(xv, wv.x, acc2[dn][0]);
      acc2[dn][1] = fmaf(xv, wv.y, acc2[dn][1]);
      acc2[dn][2] = fmaf(xv, wv.z, acc2[dn][2]);
      acc2[dn][3] = fmaf(xv, wv.w, acc2[dn][3]);
    }
  }
  {
    const float4 bs = *reinterpret_cast<const float4*>(b2 + tj * 4);
#pragma unroll
    for (int dn = 0; dn < 4; ++dn) {
      sH2[tn * 4 + dn][tj * 4 + 0] = fmaxf(acc2[dn][0] + bs.x, 0.0f);
      sH2[tn * 4 + dn][tj * 4 + 1] = fmaxf(acc2[dn][1] + bs.y, 0.0f);
      sH2[tn * 4 + dn][tj * 4 + 2] = fmaxf(acc2[dn][2] + bs.z, 0.0f);
      sH2[tn * 4 + dn][tj * 4 + 3] = fmaxf(acc2[dn][3] + bs.w, 0.0f);
    }
  }
  __syncthreads();

  {
    const int o = tid & 31;
    const int ng = tid >> 5;
    float a[8];
#pragma unroll
    for (int r = 0; r < 8; ++r) a[r] = b3[o];
#pragma unroll 2
    for (int k = 0; k < 64; ++k) {
      const float wv = W3[k * 32 + o];
#pragma unroll
      for (int r = 0; r < 8; ++r)
        a[r] = fmaf(sH2[ng * 8 + r][k], wv, a[r]);
    }
#pragma unroll
    for (int r = 0; r < 8; ++r) {
      const int nn = n0 + ng * 8 + r;
      if (nn < Nn) out[OFF_POST + ((long)b * Nn + nn) * 32 + o] = a[r];
    }
  }
}

}  // namespace

extern "C" void kernel_launch(void* const* d_in, const int* in_sizes, int n_in,
                              void* d_out, int out_size, void* d_ws, size_t ws_size,
                              hipStream_t stream) {
  const float* obs    = (const float*)d_in[0];
  const float* action = (const float*)d_in[1];
  const int* t_label  = (const int*)d_in[2];
  const int* mask     = (const int*)d_in[3];
  const float* enc_W1 = (const float*)d_in[4];
  const float* enc_b1 = (const float*)d_in[5];
  const float* enc_W2 = (const float*)d_in[6];
  const float* enc_b2 = (const float*)d_in[7];
  const float* enc_W3 = (const float*)d_in[8];
  const float* enc_b3 = (const float*)d_in[9];
  const float* gru_Wih = (const float*)d_in[10];
  const float* gru_Whh = (const float*)d_in[11];
  const float* gru_bih = (const float*)d_in[12];
  const float* gru_bhh = (const float*)d_in[13];
  const float* post_W1 = (const float*)d_in[14];
  const float* post_b1 = (const float*)d_in[15];
  const float* post_W2 = (const float*)d_in[16];
  const float* post_b2 = (const float*)d_in[17];
  const float* post_W3 = (const float*)d_in[18];
  const float* post_b3 = (const float*)d_in[19];
  const float* dec_W1 = (const float*)d_in[20];
  const float* dec_b1 = (const float*)d_in[21];
  const float* dec_W2 = (const float*)d_in[22];
  const float* dec_b2 = (const float*)d_in[23];
  const float* dec_W3 = (const float*)d_in[24];
  const float* dec_b3 = (const float*)d_in[25];
  float* out = (float*)d_out;

  enc_kernel<<<Bb * 8, 256, 0, stream>>>(obs, action, enc_W1, enc_b1, enc_W2,
                                         enc_b2, enc_W3, enc_b3, out);

  const size_t gia_bytes = (size_t)Bb * (Nn - 1) * 8 * sizeof(float);
  if (ws_size >= gia_bytes) {
    float* gia = (float*)d_ws;
    const int total = Bb * (Nn - 1);
    gia_kernel<<<(total + 255) / 256, 256, 0, stream>>>(action, gru_Wih,
                                                        gru_bih, gia);
    scan_kernel<true><<<128, 64, 0, stream>>>(
        action, mask, gru_Wih, gru_Whh, gru_bih, gru_bhh, post_W1, post_b1,
        post_W2, post_b2, post_W3, post_b3, gia, out);
  } else {
    scan_kernel<false><<<128, 64, 0, stream>>>(
        action, mask, gru_Wih, gru_Whh, gru_bih, gru_bhh, post_W1, post_b1,
        post_W2, post_b2, post_W3, post_b3, nullptr, out);
  }

  dec_kernel<<<Bb * 8, 256, 0, stream>>>(action, dec_W1, dec_b1, dec_W2, dec_b2,
                                         dec_W3, dec_b3, out);
  copy_kernel<<<2048, 256, 0, stream>>>(obs, t_label, out);
}

// Round 3
// 402.062 us; speedup vs baseline: 2.0262x; 1.7446x over previous
//
#include <hip/hip_runtime.h>
#include <hip/hip_bf16.h>

namespace {

constexpr int Bb = 512;
constexpr int Tt = 512;
constexpr int OD = 32;
constexpr int AD = 8;
constexpr int WL = 10;
constexpr int Nn = Tt - WL + 1;   // 503
constexpr int CH = OD + AD;       // 40

constexpr long SZ_PO = (long)Bb * Nn * 32;
constexpr long SZ_PR = (long)Bb * Nn * 2;
constexpr long OFF_POST   = 0;
constexpr long OFF_PRIORS = SZ_PO;
constexpr long OFF_POSTS  = OFF_PRIORS + SZ_PR;
constexpr long OFF_XTRAJ  = OFF_POSTS + SZ_PR;
constexpr long OFF_TGT    = OFF_XTRAJ + SZ_PR;
constexpr long OFF_LAB    = OFF_TGT + SZ_PO;

// ---- packed weight buffer (bf16 MFMA B-fragments), device-global ----
constexpr int PK_W1  = 0;              // 13 kb x 4 jb
constexpr int PK_W2  = 26624;          // 2 x 4
constexpr int PK_W3  = 30720;          // 2 x 1
constexpr int PK_DW1 = 31744;          // 1 x 4
constexpr int PK_DW2 = 33792;          // 2 x 4
constexpr int PK_DW3 = 37888;          // 2 x 2
constexpr int PK_TOTAL = 39936;

typedef __attribute__((ext_vector_type(8))) short bf16x8;
typedef __attribute__((ext_vector_type(4))) float f32x4;

__device__ __align__(16) short g_pack[PK_TOTAL];

__device__ __forceinline__ f32x4 mfma16(bf16x8 a, bf16x8 b, f32x4 c) {
  return __builtin_amdgcn_mfma_f32_16x16x32_bf16(a, b, c, 0, 0, 0);
}

__device__ __forceinline__ unsigned short f2bf(float x) {
  unsigned int u = __float_as_uint(x);
  unsigned int r = u + 0x7fffu + ((u >> 16) & 1u);
  return (unsigned short)(r >> 16);
}

__device__ __forceinline__ float sigmoidf_(float x) {
  return 1.0f / (1.0f + __expf(-x));
}
__device__ __forceinline__ float tanh_(float x) {
  return 1.0f - 2.0f / (__expf(2.0f * x) + 1.0f);
}

template <int CTRL>
__device__ __forceinline__ float dpp_add(float x) {
  int y = __builtin_amdgcn_update_dpp(0, __float_as_int(x), CTRL, 0xf, 0xf, false);
  return x + __int_as_float(y);
}
__device__ __forceinline__ float row16_allsum(float x) {
  x = dpp_add<0xB1>(x);
  x = dpp_add<0x4E>(x);
  x = dpp_add<0x141>(x);
  x = dpp_add<0x140>(x);
  return x;
}

// ---------------- weight prepack ----------------
// k' = w*40 + c permutation for W1 so A-fragments are k-contiguous in the
// staged oa tile; all weights stored in per-lane MFMA B-fragment order:
// element(kb,jb,lane,j) = B[kb*32 + (lane>>4)*8 + j][jb*16 + (lane&15)]
__global__ __launch_bounds__(256) void pack_kernel(
    const float* __restrict__ W1, const float* __restrict__ W2,
    const float* __restrict__ W3, const float* __restrict__ dW1,
    const float* __restrict__ dW2, const float* __restrict__ dW3) {
  const int idx = blockIdx.x * 256 + threadIdx.x;
  if (idx >= PK_TOTAL) return;
  float v = 0.0f;
  int base, r;
  if (idx < PK_W2) {
    base = PK_W1; r = idx - base;
    const int frag = r >> 9, inner = r & 511;
    const int lane = inner >> 3, j = inner & 7;
    const int kb = frag >> 2, jb = frag & 3;
    const int col = lane & 15;
    const int kp = kb * 32 + ((lane >> 4) << 3) + j;
    if (kp < 400) {
      const int w = kp / 40, c = kp - w * 40;
      v = W1[(c * 10 + w) * 64 + jb * 16 + col];
    }
  } else if (idx < PK_W3) {
    base = PK_W2; r = idx - base;
    const int frag = r >> 9, inner = r & 511;
    const int lane = inner >> 3, j = inner & 7;
    const int kb = frag >> 2, jb = frag & 3;
    const int col = lane & 15;
    const int k = kb * 32 + ((lane >> 4) << 3) + j;
    v = W2[k * 64 + jb * 16 + col];
  } else if (idx < PK_DW1) {
    base = PK_W3; r = idx - base;
    const int frag = r >> 9, inner = r & 511;
    const int lane = inner >> 3, j = inner & 7;
    const int kb = frag;
    const int col = lane & 15;
    const int k = kb * 32 + ((lane >> 4) << 3) + j;
    v = (col < 2) ? W3[k * 2 + col] : 0.0f;
  } else if (idx < PK_DW2) {
    base = PK_DW1; r = idx - base;
    const int frag = r >> 9, inner = r & 511;
    const int lane = inner >> 3, j = inner & 7;
    const int jb = frag;
    const int col = lane & 15;
    const int k = ((lane >> 4) << 3) + j;
    v = (k < 10) ? dW1[k * 64 + jb * 16 + col] : 0.0f;
  } else if (idx < PK_DW3) {
    base = PK_DW2; r = idx - base;
    const int frag = r >> 9, inner = r & 511;
    const int lane = inner >> 3, j = inner & 7;
    const int kb = frag >> 2, jb = frag & 3;
    const int col = lane & 15;
    const int k = kb * 32 + ((lane >> 4) << 3) + j;
    v = dW2[k * 64 + jb * 16 + col];
  } else {
    base = PK_DW3; r = idx - base;
    const int frag = r >> 9, inner = r & 511;
    const int lane = inner >> 3, j = inner & 7;
    const int kb = frag >> 1, jb = frag & 1;
    const int col = lane & 15;
    const int k = kb * 32 + ((lane >> 4) << 3) + j;
    v = dW3[k * 32 + jb * 16 + col];
  }
  g_pack[idx] = (short)f2bf(v);
}

// ---------------- copies ----------------
__global__ void copy_kernel(const float* __restrict__ obs,
                            const int* __restrict__ tlab,
                            float* __restrict__ out) {
  const int total4 = (int)(SZ_PO / 4);
  const int totalL = Bb * Nn;
  const int stride = gridDim.x * blockDim.x;
  float4* out4 = reinterpret_cast<float4*>(out + OFF_TGT);
  const float4* obs4 = reinterpret_cast<const float4*>(obs);
  for (int idx = blockIdx.x * blockDim.x + threadIdx.x;
       idx < total4 + totalL; idx += stride) {
    if (idx < total4) {
      const int b = idx / (Nn * 8);
      const int r = idx - b * (Nn * 8);
      const int n = r >> 3;
      const int c4 = r & 7;
      out4[idx] = obs4[((long)b * Tt + n + WL - 1) * 8 + c4];
    } else {
      const int j = idx - total4;
      const int b = j / Nn;
      const int n = j - b * Nn;
      out[OFF_LAB + j] = (float)tlab[(long)b * Tt + n + WL - 1];
    }
  }
}

// ---------------- encoder (MFMA) ----------------
__global__ __launch_bounds__(256) void enc_mfma(
    const float* __restrict__ obs, const float* __restrict__ act,
    const float* __restrict__ b1, const float* __restrict__ b2,
    const float* __restrict__ b3, float* __restrict__ out) {
  __shared__ __align__(16) unsigned short sA[74 * 40];
  __shared__ __align__(16) unsigned short sH1[64 * 64];
  __shared__ __align__(16) unsigned short sH2[64 * 64];
  const int b = blockIdx.x >> 3;
  const int n0 = (blockIdx.x & 7) << 6;
  const int tid = threadIdx.x;
  const int lane = tid & 63, wv = tid >> 6;
  const int q = lane >> 4, lr = lane & 15;
  const int nl = wv * 16 + lr;

  for (int e = tid; e < 74 * 40; e += 256) {
    const int row = e / 40, c = e - row * 40;
    int t = n0 + row; t = t < Tt ? t : Tt - 1;
    const float v = (c < OD) ? obs[((long)b * Tt + t) * OD + c]
                             : act[((long)b * Tt + t) * AD + c - OD];
    sA[e] = f2bf(v);
  }
  __syncthreads();

  const char* sAb = (const char*)sA;
  // layer 1: K' = 416 (13 kb), k' = w*40 + c
  f32x4 acc[4] = {{0,0,0,0},{0,0,0,0},{0,0,0,0},{0,0,0,0}};
  {
    int c0 = q * 8, w = 0;
#pragma unroll
    for (int kb = 0; kb < 13; ++kb) {
      const bf16x8 a = *(const bf16x8*)(sAb + (nl + w) * 80 + c0 * 2);
#pragma unroll
      for (int jb = 0; jb < 4; ++jb) {
        const bf16x8 bw =
            *(const bf16x8*)&g_pack[PK_W1 + ((kb * 4 + jb) * 64 + lane) * 8];
        acc[jb] = mfma16(a, bw, acc[jb]);
      }
      c0 += 32;
      if (c0 >= 40) { c0 -= 40; ++w; }
    }
  }
  {
#pragma unroll
    for (int jb = 0; jb < 4; ++jb) {
      const float bb = b1[jb * 16 + lr];
#pragma unroll
      for (int r = 0; r < 4; ++r) {
        const int grow = wv * 16 + q * 4 + r;
        const int col = jb * 16 + lr;
        const float v = fmaxf(acc[jb][r] + bb, 0.0f);
        const int byte = (grow * 128 + col * 2) ^ ((grow & 7) << 4);
        *(unsigned short*)((char*)sH1 + byte) = f2bf(v);
      }
    }
  }
  __syncthreads();

  // layer 2: 64x64
  f32x4 ac2[4] = {{0,0,0,0},{0,0,0,0},{0,0,0,0},{0,0,0,0}};
#pragma unroll
  for (int kb = 0; kb < 2; ++kb) {
    const int byte = (nl * 128 + kb * 64 + q * 16) ^ ((lr & 7) << 4);
    const bf16x8 a = *(const bf16x8*)((const char*)sH1 + byte);
#pragma unroll
    for (int jb = 0; jb < 4; ++jb) {
      const bf16x8 bw =
          *(const bf16x8*)&g_pack[PK_W2 + ((kb * 4 + jb) * 64 + lane) * 8];
      ac2[jb] = mfma16(a, bw, ac2[jb]);
    }
  }
  {
#pragma unroll
    for (int jb = 0; jb < 4; ++jb) {
      const float bb = b2[jb * 16 + lr];
#pragma unroll
      for (int r = 0; r < 4; ++r) {
        const int grow = wv * 16 + q * 4 + r;
        const int col = jb * 16 + lr;
        const float v = fmaxf(ac2[jb][r] + bb, 0.0f);
        const int byte = (grow * 128 + col * 2) ^ ((grow & 7) << 4);
        *(unsigned short*)((char*)sH2 + byte) = f2bf(v);
      }
    }
  }
  __syncthreads();

  // layer 3: 64 -> 2 (padded to 16 cols)
  f32x4 ac3 = {0, 0, 0, 0};
#pragma unroll
  for (int kb = 0; kb < 2; ++kb) {
    const int byte = (nl * 128 + kb * 64 + q * 16) ^ ((lr & 7) << 4);
    const bf16x8 a = *(const bf16x8*)((const char*)sH2 + byte);
    const bf16x8 bw = *(const bf16x8*)&g_pack[PK_W3 + (kb * 64 + lane) * 8];
    ac3 = mfma16(a, bw, ac3);
  }
  if (lr < 2) {
    const float bb = b3[lr];
#pragma unroll
    for (int r = 0; r < 4; ++r) {
      const int grow = wv * 16 + q * 4 + r;
      const int n = n0 + grow;
      if (n < Nn) out[OFF_PRIORS + ((long)b * Nn + n) * 2 + lr] = ac3[r] + bb;
    }
  }
}

// ---------------- decoder (MFMA) ----------------
__global__ __launch_bounds__(256) void dec_mfma(
    const float* __restrict__ act, const float* __restrict__ b1,
    const float* __restrict__ b2, const float* __restrict__ b3,
    float* __restrict__ out) {
  __shared__ __align__(16) unsigned short sD[64 * 32];
  __shared__ __align__(16) unsigned short sH1[64 * 64];
  __shared__ __align__(16) unsigned short sH2[64 * 64];
  const int b = blockIdx.x >> 3;
  const int n0 = (blockIdx.x & 7) << 6;
  const int tid = threadIdx.x;
  const int lane = tid & 63, wv = tid >> 6;
  const int q = lane >> 4, lr = lane & 15;
  const int nl = wv * 16 + lr;
  const float* posts = out + OFF_POSTS;

  for (int e = tid; e < 64 * 32; e += 256) {
    const int row = e >> 5, c = e & 31;
    int n = n0 + row; n = n < Nn ? n : Nn - 1;
    float v = 0.0f;
    if (c < 2) v = posts[((long)b * Nn + n) * 2 + c];
    else if (c < 10) v = act[((long)b * Tt + n + WL - 1) * AD + c - 2];
    const int byte = (row * 64 + c * 2) ^ ((row & 3) << 4);
    *(unsigned short*)((char*)sD + byte) = f2bf(v);
  }
  __syncthreads();

  // layer 1: K = 10 (padded 32)
  f32x4 acc[4] = {{0,0,0,0},{0,0,0,0},{0,0,0,0},{0,0,0,0}};
  {
    const int byte = (nl * 64 + q * 16) ^ ((nl & 3) << 4);
    const bf16x8 a = *(const bf16x8*)((const char*)sD + byte);
#pragma unroll
    for (int jb = 0; jb < 4; ++jb) {
      const bf16x8 bw = *(const bf16x8*)&g_pack[PK_DW1 + (jb * 64 + lane) * 8];
      acc[jb] = mfma16(a, bw, acc[jb]);
    }
  }
  {
#pragma unroll
    for (int jb = 0; jb < 4; ++jb) {
      const float bb = b1[jb * 16 + lr];
#pragma unroll
      for (int r = 0; r < 4; ++r) {
        const int grow = wv * 16 + q * 4 + r;
        const int col = jb * 16 + lr;
        const float v = fmaxf(acc[jb][r] + bb, 0.0f);
        const int byte = (grow * 128 + col * 2) ^ ((grow & 7) << 4);
        *(unsigned short*)((char*)sH1 + byte) = f2bf(v);
      }
    }
  }
  __syncthreads();

  f32x4 ac2[4] = {{0,0,0,0},{0,0,0,0},{0,0,0,0},{0,0,0,0}};
#pragma unroll
  for (int kb = 0; kb < 2; ++kb) {
    const int byte = (nl * 128 + kb * 64 + q * 16) ^ ((lr & 7) << 4);
    const bf16x8 a = *(const bf16x8*)((const char*)sH1 + byte);
#pragma unroll
    for (int jb = 0; jb < 4; ++jb) {
      const bf16x8 bw =
          *(const bf16x8*)&g_pack[PK_DW2 + ((kb * 4 + jb) * 64 + lane) * 8];
      ac2[jb] = mfma16(a, bw, ac2[jb]);
    }
  }
  {
#pragma unroll
    for (int jb = 0; jb < 4; ++jb) {
      const float bb = b2[jb * 16 + lr];
#pragma unroll
      for (int r = 0; r < 4; ++r) {
        const int grow = wv * 16 + q * 4 + r;
        const int col = jb * 16 + lr;
        const float v = fmaxf(ac2[jb][r] + bb, 0.0f);
        const int byte = (grow * 128 + col * 2) ^ ((grow & 7) << 4);
        *(unsigned short*)((char*)sH2 + byte) = f2bf(v);
      }
    }
  }
  __syncthreads();

  // layer 3: 64 -> 32
  f32x4 ac3[2] = {{0,0,0,0},{0,0,0,0}};
#pragma unroll
  for (int kb = 0; kb < 2; ++kb) {
    const int byte = (nl * 128 + kb * 64 + q * 16) ^ ((lr & 7) << 4);
    const bf16x8 a = *(const bf16x8*)((const char*)sH2 + byte);
#pragma unroll
    for (int jb = 0; jb < 2; ++jb) {
      const bf16x8 bw =
          *(const bf16x8*)&g_pack[PK_DW3 + ((kb * 2 + jb) * 64 + lane) * 8];
      ac3[jb] = mfma16(a, bw, ac3[jb]);
    }
  }
#pragma unroll
  for (int jb = 0; jb < 2; ++jb) {
    const int o = jb * 16 + lr;
    const float bb = b3[o];
#pragma unroll
    for (int r = 0; r < 4; ++r) {
      const int grow = wv * 16 + q * 4 + r;
      const int n = n0 + grow;
      if (n < Nn) out[OFF_POST + ((long)b * Nn + n) * 32 + o] = ac3[jb][r] + bb;
    }
  }
}

// ---------------- gia precompute ----------------
__global__ __launch_bounds__(256) void gia_kernel(const float* __restrict__ act,
                                                  const float* __restrict__ Wih,
                                                  const float* __restrict__ bih,
                                                  float* __restrict__ gia) {
  const int idx = blockIdx.x * 256 + threadIdx.x;
  const int total = Bb * (Nn - 1);
  if (idx >= total) return;
  const int g = idx / (Nn - 1);
  const int t = idx - g * (Nn - 1);
  const float* a = act + ((long)g * Tt + WL - 1 + t) * AD;
  const float4 a0 = *reinterpret_cast<const float4*>(a);
  const float4 a1 = *reinterpret_cast<const float4*>(a + 4);
  float r[8];
#pragma unroll
  for (int q = 0; q < 6; ++q) {
    float acc = bih[q];
    acc = fmaf(a0.x, Wih[0 * 6 + q], acc);
    acc = fmaf(a0.y, Wih[1 * 6 + q], acc);
    acc = fmaf(a0.z, Wih[2 * 6 + q], acc);
    acc = fmaf(a0.w, Wih[3 * 6 + q], acc);
    acc = fmaf(a1.x, Wih[4 * 6 + q], acc);
    acc = fmaf(a1.y, Wih[5 * 6 + q], acc);
    acc = fmaf(a1.z, Wih[6 * 6 + q], acc);
    acc = fmaf(a1.w, Wih[7 * 6 + q], acc);
    r[q] = acc;
  }
  r[6] = 0.f;
  r[7] = 0.f;
  float4* o = reinterpret_cast<float4*>(gia + (long)idx * 8);
  o[0] = make_float4(r[0], r[1], r[2], r[3]);
  o[1] = make_float4(r[4], r[5], r[6], r[7]);
}

// ---------------- sequential GRU + post-MLP scan ----------------
template <bool USE_GIA>
__global__ __launch_bounds__(64) void scan_kernel(
    const float* __restrict__ act, const int* __restrict__ mask,
    const float* __restrict__ Wih, const float* __restrict__ Whh,
    const float* __restrict__ bih, const float* __restrict__ bhh,
    const float* __restrict__ pW1, const float* __restrict__ pb1,
    const float* __restrict__ pW2, const float* __restrict__ pb2,
    const float* __restrict__ pW3, const float* __restrict__ pb3,
    const float* __restrict__ gia,
    float* __restrict__ out) {
  const int tid = threadIdx.x;
  const int lane = tid & 15;
  const int g = (blockIdx.x * 64 + tid) >> 4;

  float wih8[6], wih9[6], whh0[6], whh1[6], bhhv[6];
#pragma unroll
  for (int q = 0; q < 6; ++q) {
    wih8[q] = Wih[8 * 6 + q];
    wih9[q] = Wih[9 * 6 + q];
    whh0[q] = Whh[q];
    whh1[q] = Whh[6 + q];
    bhhv[q] = bhh[q];
  }
  float wihA[8][6];
  float bihv[6];
  if constexpr (!USE_GIA) {
#pragma unroll
    for (int i = 0; i < 8; ++i)
#pragma unroll
      for (int q = 0; q < 6; ++q) wihA[i][q] = Wih[i * 6 + q];
#pragma unroll
    for (int q = 0; q < 6; ++q) bihv[q] = bih[q];
  }

  const float w1c0 = pW1[lane], w1c1 = pW1[16 + lane], b1v = pb1[lane];
  float w2c[16];
#pragma unroll
  for (int k = 0; k < 16; ++k) w2c[k] = pW2[k * 16 + lane];
  const float b2v = pb2[lane];
  const float w3a = pW3[lane * 2], w3b = pW3[lane * 2 + 1];
  const float b3a = pb3[0], b3b = pb3[1];

  const float* priors = out + OFF_PRIORS;
  float* posts = out + OFF_POSTS;
  float* xtraj = out + OFF_XTRAJ;
  const long pbase = (long)g * Nn;
  const float* giap = gia + (long)g * (Nn - 1) * 8;
  const float* aptr = act + ((long)g * Tt + WL - 1) * 8;

  const float2 s0v = *reinterpret_cast<const float2*>(priors + pbase * 2);
  float x0p = 0.f, x1p = 0.f;
  float s0p = s0v.x, s1p = s0v.y;
  if (lane == 0)
    *reinterpret_cast<float2*>(xtraj + pbase * 2) = make_float2(0.f, 0.f);
  if (lane == 1)
    *reinterpret_cast<float2*>(posts + pbase * 2) = make_float2(s0p, s1p);

  float4 gf0, gf1, an0, an1;
  if constexpr (USE_GIA) {
    gf0 = *reinterpret_cast<const float4*>(giap);
    gf1 = *reinterpret_cast<const float4*>(giap + 4);
  } else {
    an0 = *reinterpret_cast<const float4*>(aptr);
    an1 = *reinterpret_cast<const float4*>(aptr + 4);
  }
  float2 prn = s0v;
  int mn = mask[pbase];

  for (int t = 0; t < Nn - 1; ++t) {
    const float4 g0 = gf0, g1 = gf1, a0 = an0, a1 = an1;
    const float2 pr = prn;
    const int m = mn;
    const int tn1 = (t + 1 < Nn - 1) ? t + 1 : Nn - 2;
    if constexpr (USE_GIA) {
      gf0 = *reinterpret_cast<const float4*>(giap + (long)tn1 * 8);
      gf1 = *reinterpret_cast<const float4*>(giap + (long)tn1 * 8 + 4);
    } else {
      an0 = *reinterpret_cast<const float4*>(aptr + (long)tn1 * 8);
      an1 = *reinterpret_cast<const float4*>(aptr + (long)tn1 * 8 + 4);
    }
    prn = *reinterpret_cast<const float2*>(priors + (pbase + t + 1) * 2);
    mn = mask[pbase + t + 1];

    const float st0 = m ? pr.x : s0p;
    const float st1 = m ? pr.y : s1p;

    float giq[6], ghq[6];
    float gbase[6];
    if constexpr (USE_GIA) {
      gbase[0] = g0.x; gbase[1] = g0.y; gbase[2] = g0.z;
      gbase[3] = g0.w; gbase[4] = g1.x; gbase[5] = g1.y;
    } else {
#pragma unroll
      for (int q = 0; q < 6; ++q) {
        float acc = bihv[q];
        acc = fmaf(a0.x, wihA[0][q], acc);
        acc = fmaf(a0.y, wihA[1][q], acc);
        acc = fmaf(a0.z, wihA[2][q], acc);
        acc = fmaf(a0.w, wihA[3][q], acc);
        acc = fmaf(a1.x, wihA[4][q], acc);
        acc = fmaf(a1.y, wihA[5][q], acc);
        acc = fmaf(a1.z, wihA[6][q], acc);
        acc = fmaf(a1.w, wihA[7][q], acc);
        gbase[q] = acc;
      }
    }
#pragma unroll
    for (int q = 0; q < 6; ++q) {
      giq[q] = fmaf(st1, wih9[q], fmaf(st0, wih8[q], gbase[q]));
      ghq[q] = fmaf(x1p, whh1[q], fmaf(x0p, whh0[q], bhhv[q]));
    }
    const float r0 = sigmoidf_(giq[0] + ghq[0]);
    const float r1 = sigmoidf_(giq[1] + ghq[1]);
    const float z0 = sigmoidf_(giq[2] + ghq[2]);
    const float z1 = sigmoidf_(giq[3] + ghq[3]);
    const float nn0 = tanh_(fmaf(r0, ghq[4], giq[4]));
    const float nn1 = tanh_(fmaf(r1, ghq[5], giq[5]));
    const float xn0 = fmaf(z0, x0p - nn0, nn0);
    const float xn1 = fmaf(z1, x1p - nn1, nn1);

    const float h1 = fmaxf(fmaf(xn1, w1c1, fmaf(xn0, w1c0, b1v)), 0.0f);
    float ha[16];
#pragma unroll
    for (int k = 0; k < 16; ++k) ha[k] = __shfl(h1, k, 16);
    float q0 = fmaf(ha[0], w2c[0], b2v);
    q0 = fmaf(ha[1], w2c[1], q0);
    q0 = fmaf(ha[2], w2c[2], q0);
    q0 = fmaf(ha[3], w2c[3], q0);
    float q1 = ha[4] * w2c[4];
    q1 = fmaf(ha[5], w2c[5], q1);
    q1 = fmaf(ha[6], w2c[6], q1);
    q1 = fmaf(ha[7], w2c[7], q1);
    float q2 = ha[8] * w2c[8];
    q2 = fmaf(ha[9], w2c[9], q2);
    q2 = fmaf(ha[10], w2c[10], q2);
    q2 = fmaf(ha[11], w2c[11], q2);
    float q3 = ha[12] * w2c[12];
    q3 = fmaf(ha[13], w2c[13], q3);
    q3 = fmaf(ha[14], w2c[14], q3);
    q3 = fmaf(ha[15], w2c[15], q3);
    const float h2 = fmaxf((q0 + q1) + (q2 + q3), 0.0f);

    float p0 = h2 * w3a;
    float p1 = h2 * w3b;
    p0 = row16_allsum(p0);
    p1 = row16_allsum(p1);
    const float sn0 = p0 + b3a;
    const float sn1 = p1 + b3b;

    if (lane == 0)
      *reinterpret_cast<float2*>(xtraj + (pbase + t + 1) * 2) =
          make_float2(xn0, xn1);
    if (lane == 1)
      *reinterpret_cast<float2*>(posts + (pbase + t + 1) * 2) =
          make_float2(sn0, sn1);
    x0p = xn0; x1p = xn1; s0p = sn0; s1p = sn1;
  }
}

}  // namespace

extern "C" void kernel_launch(void* const* d_in, const int* in_sizes, int n_in,
                              void* d_out, int out_size, void* d_ws, size_t ws_size,
                              hipStream_t stream) {
  const float* obs    = (const float*)d_in[0];
  const float* action = (const float*)d_in[1];
  const int* t_label  = (const int*)d_in[2];
  const int* mask     = (const int*)d_in[3];
  const float* enc_W1 = (const float*)d_in[4];
  const float* enc_b1 = (const float*)d_in[5];
  const float* enc_W2 = (const float*)d_in[6];
  const float* enc_b2 = (const float*)d_in[7];
  const float* enc_W3 = (const float*)d_in[8];
  const float* enc_b3 = (const float*)d_in[9];
  const float* gru_Wih = (const float*)d_in[10];
  const float* gru_Whh = (const float*)d_in[11];
  const float* gru_bih = (const float*)d_in[12];
  const float* gru_bhh = (const float*)d_in[13];
  const float* post_W1 = (const float*)d_in[14];
  const float* post_b1 = (const float*)d_in[15];
  const float* post_W2 = (const float*)d_in[16];
  const float* post_b2 = (const float*)d_in[17];
  const float* post_W3 = (const float*)d_in[18];
  const float* post_b3 = (const float*)d_in[19];
  const float* dec_W1 = (const float*)d_in[20];
  const float* dec_b1 = (const float*)d_in[21];
  const float* dec_W2 = (const float*)d_in[22];
  const float* dec_b2 = (const float*)d_in[23];
  const float* dec_W3 = (const float*)d_in[24];
  const float* dec_b3 = (const float*)d_in[25];
  float* out = (float*)d_out;

  pack_kernel<<<(PK_TOTAL + 255) / 256, 256, 0, stream>>>(
      enc_W1, enc_W2, enc_W3, dec_W1, dec_W2, dec_W3);

  enc_mfma<<<Bb * 8, 256, 0, stream>>>(obs, action, enc_b1, enc_b2, enc_b3,
                                       out);

  const size_t gia_bytes = (size_t)Bb * (Nn - 1) * 8 * sizeof(float);
  if (ws_size >= gia_bytes) {
    float* gia = (float*)d_ws;
    const int total = Bb * (Nn - 1);
    gia_kernel<<<(total + 255) / 256, 256, 0, stream>>>(action, gru_Wih,
                                                        gru_bih, gia);
    scan_kernel<true><<<128, 64, 0, stream>>>(
        action, mask, gru_Wih, gru_Whh, gru_bih, gru_bhh, post_W1, post_b1,
        post_W2, post_b2, post_W3, post_b3, gia, out);
  } else {
    scan_kernel<false><<<128, 64, 0, stream>>>(
        action, mask, gru_Wih, gru_Whh, gru_bih, gru_bhh, post_W1, post_b1,
        post_W2, post_b2, post_W3, post_b3, nullptr, out);
  }

  dec_mfma<<<Bb * 8, 256, 0, stream>>>(action, dec_b1, dec_b2, dec_b3, out);
  copy_kernel<<<2048, 256, 0, stream>>>(obs, t_label, out);
}

// Round 4
// 300.549 us; speedup vs baseline: 2.7106x; 1.3378x over previous
//
#include <hip/hip_runtime.h>
#include <hip/hip_bf16.h>

namespace {

constexpr int Bb = 512;
constexpr int Tt = 512;
constexpr int OD = 32;
constexpr int AD = 8;
constexpr int WL = 10;
constexpr int Nn = Tt - WL + 1;   // 503
constexpr int CH = OD + AD;       // 40
constexpr int REC_T = 504;        // padded step count for scan records

constexpr long SZ_PO = (long)Bb * Nn * 32;
constexpr long SZ_PR = (long)Bb * Nn * 2;
constexpr long OFF_POST   = 0;
constexpr long OFF_PRIORS = SZ_PO;
constexpr long OFF_POSTS  = OFF_PRIORS + SZ_PR;
constexpr long OFF_XTRAJ  = OFF_POSTS + SZ_PR;
constexpr long OFF_TGT    = OFF_XTRAJ + SZ_PR;
constexpr long OFF_LAB    = OFF_TGT + SZ_PO;

// ---- packed weight buffer (bf16 MFMA B-fragments), device-global ----
constexpr int PK_W1  = 0;              // 13 kb x 4 jb
constexpr int PK_W2  = 26624;          // 2 x 4
constexpr int PK_W3  = 30720;          // 2 x 1
constexpr int PK_DW1 = 31744;          // 1 x 4
constexpr int PK_DW2 = 33792;          // 2 x 4
constexpr int PK_DW3 = 37888;          // 2 x 2
constexpr int PK_TOTAL = 39936;

typedef __attribute__((ext_vector_type(8))) short bf16x8;
typedef __attribute__((ext_vector_type(4))) float f32x4;

__device__ __align__(16) short g_pack[PK_TOTAL];

__device__ __forceinline__ f32x4 mfma16(bf16x8 a, bf16x8 b, f32x4 c) {
  return __builtin_amdgcn_mfma_f32_16x16x32_bf16(a, b, c, 0, 0, 0);
}

__device__ __forceinline__ unsigned short f2bf(float x) {
  unsigned int u = __float_as_uint(x);
  unsigned int r = u + 0x7fffu + ((u >> 16) & 1u);
  return (unsigned short)(r >> 16);
}

__device__ __forceinline__ float sigmoidf_(float x) {
  return 1.0f / (1.0f + __expf(-x));
}
__device__ __forceinline__ float tanh_(float x) {
  return 1.0f - 2.0f / (__expf(2.0f * x) + 1.0f);
}

template <int CTRL>
__device__ __forceinline__ float dpp_add(float x) {
  int y = __builtin_amdgcn_update_dpp(0, __float_as_int(x), CTRL, 0xf, 0xf, false);
  return x + __int_as_float(y);
}
template <int CTRL>
__device__ __forceinline__ float dpp_mov(float x) {
  return __int_as_float(
      __builtin_amdgcn_update_dpp(0, __float_as_int(x), CTRL, 0xf, 0xf, false));
}
__device__ __forceinline__ float row16_allsum(float x) {
  x = dpp_add<0xB1>(x);   // xor 1
  x = dpp_add<0x4E>(x);   // xor 2
  x = dpp_add<0x141>(x);  // xor 7 (row_half_mirror)
  x = dpp_add<0x140>(x);  // xor 15 (row_mirror)
  return x;
}

// ---------------- weight prepack ----------------
__global__ __launch_bounds__(256) void pack_kernel(
    const float* __restrict__ W1, const float* __restrict__ W2,
    const float* __restrict__ W3, const float* __restrict__ dW1,
    const float* __restrict__ dW2, const float* __restrict__ dW3) {
  const int idx = blockIdx.x * 256 + threadIdx.x;
  if (idx >= PK_TOTAL) return;
  float v = 0.0f;
  int base, r;
  if (idx < PK_W2) {
    base = PK_W1; r = idx - base;
    const int frag = r >> 9, inner = r & 511;
    const int lane = inner >> 3, j = inner & 7;
    const int kb = frag >> 2, jb = frag & 3;
    const int col = lane & 15;
    const int kp = kb * 32 + ((lane >> 4) << 3) + j;
    if (kp < 400) {
      const int w = kp / 40, c = kp - w * 40;
      v = W1[(c * 10 + w) * 64 + jb * 16 + col];
    }
  } else if (idx < PK_W3) {
    base = PK_W2; r = idx - base;
    const int frag = r >> 9, inner = r & 511;
    const int lane = inner >> 3, j = inner & 7;
    const int kb = frag >> 2, jb = frag & 3;
    const int col = lane & 15;
    const int k = kb * 32 + ((lane >> 4) << 3) + j;
    v = W2[k * 64 + jb * 16 + col];
  } else if (idx < PK_DW1) {
    base = PK_W3; r = idx - base;
    const int frag = r >> 9, inner = r & 511;
    const int lane = inner >> 3, j = inner & 7;
    const int kb = frag;
    const int col = lane & 15;
    const int k = kb * 32 + ((lane >> 4) << 3) + j;
    v = (col < 2) ? W3[k * 2 + col] : 0.0f;
  } else if (idx < PK_DW2) {
    base = PK_DW1; r = idx - base;
    const int frag = r >> 9, inner = r & 511;
    const int lane = inner >> 3, j = inner & 7;
    const int jb = frag;
    const int col = lane & 15;
    const int k = ((lane >> 4) << 3) + j;
    v = (k < 10) ? dW1[k * 64 + jb * 16 + col] : 0.0f;
  } else if (idx < PK_DW3) {
    base = PK_DW2; r = idx - base;
    const int frag = r >> 9, inner = r & 511;
    const int lane = inner >> 3, j = inner & 7;
    const int kb = frag >> 2, jb = frag & 3;
    const int col = lane & 15;
    const int k = kb * 32 + ((lane >> 4) << 3) + j;
    v = dW2[k * 64 + jb * 16 + col];
  } else {
    base = PK_DW3; r = idx - base;
    const int frag = r >> 9, inner = r & 511;
    const int lane = inner >> 3, j = inner & 7;
    const int kb = frag >> 1, jb = frag & 1;
    const int col = lane & 15;
    const int k = kb * 32 + ((lane >> 4) << 3) + j;
    v = dW3[k * 32 + jb * 16 + col];
  }
  g_pack[idx] = (short)f2bf(v);
}

// ---------------- copies ----------------
__global__ void copy_kernel(const float* __restrict__ obs,
                            const int* __restrict__ tlab,
                            float* __restrict__ out) {
  const int total4 = (int)(SZ_PO / 4);
  const int totalL = Bb * Nn;
  const int stride = gridDim.x * blockDim.x;
  float4* out4 = reinterpret_cast<float4*>(out + OFF_TGT);
  const float4* obs4 = reinterpret_cast<const float4*>(obs);
  for (int idx = blockIdx.x * blockDim.x + threadIdx.x;
       idx < total4 + totalL; idx += stride) {
    if (idx < total4) {
      const int b = idx / (Nn * 8);
      const int r = idx - b * (Nn * 8);
      const int n = r >> 3;
      const int c4 = r & 7;
      out4[idx] = obs4[((long)b * Tt + n + WL - 1) * 8 + c4];
    } else {
      const int j = idx - total4;
      const int b = j / Nn;
      const int n = j - b * Nn;
      out[OFF_LAB + j] = (float)tlab[(long)b * Tt + n + WL - 1];
    }
  }
}

// ---------------- encoder (MFMA) ----------------
__global__ __launch_bounds__(256) void enc_mfma(
    const float* __restrict__ obs, const float* __restrict__ act,
    const float* __restrict__ b1, const float* __restrict__ b2,
    const float* __restrict__ b3, float* __restrict__ out) {
  __shared__ __align__(16) unsigned short sA[74 * 40];
  __shared__ __align__(16) unsigned short sH1[64 * 64];
  __shared__ __align__(16) unsigned short sH2[64 * 64];
  const int b = blockIdx.x >> 3;
  const int n0 = (blockIdx.x & 7) << 6;
  const int tid = threadIdx.x;
  const int lane = tid & 63, wv = tid >> 6;
  const int q = lane >> 4, lr = lane & 15;
  const int nl = wv * 16 + lr;

  for (int e = tid; e < 74 * 40; e += 256) {
    const int row = e / 40, c = e - row * 40;
    int t = n0 + row; t = t < Tt ? t : Tt - 1;
    const float v = (c < OD) ? obs[((long)b * Tt + t) * OD + c]
                             : act[((long)b * Tt + t) * AD + c - OD];
    sA[e] = f2bf(v);
  }
  __syncthreads();

  const char* sAb = (const char*)sA;
  f32x4 acc[4] = {{0,0,0,0},{0,0,0,0},{0,0,0,0},{0,0,0,0}};
  {
    int c0 = q * 8, w = 0;
#pragma unroll
    for (int kb = 0; kb < 13; ++kb) {
      const bf16x8 a = *(const bf16x8*)(sAb + (nl + w) * 80 + c0 * 2);
#pragma unroll
      for (int jb = 0; jb < 4; ++jb) {
        const bf16x8 bw =
            *(const bf16x8*)&g_pack[PK_W1 + ((kb * 4 + jb) * 64 + lane) * 8];
        acc[jb] = mfma16(a, bw, acc[jb]);
      }
      c0 += 32;
      if (c0 >= 40) { c0 -= 40; ++w; }
    }
  }
  {
#pragma unroll
    for (int jb = 0; jb < 4; ++jb) {
      const float bb = b1[jb * 16 + lr];
#pragma unroll
      for (int r = 0; r < 4; ++r) {
        const int grow = wv * 16 + q * 4 + r;
        const int col = jb * 16 + lr;
        const float v = fmaxf(acc[jb][r] + bb, 0.0f);
        const int byte = (grow * 128 + col * 2) ^ ((grow & 7) << 4);
        *(unsigned short*)((char*)sH1 + byte) = f2bf(v);
      }
    }
  }
  __syncthreads();

  f32x4 ac2[4] = {{0,0,0,0},{0,0,0,0},{0,0,0,0},{0,0,0,0}};
#pragma unroll
  for (int kb = 0; kb < 2; ++kb) {
    const int byte = (nl * 128 + kb * 64 + q * 16) ^ ((lr & 7) << 4);
    const bf16x8 a = *(const bf16x8*)((const char*)sH1 + byte);
#pragma unroll
    for (int jb = 0; jb < 4; ++jb) {
      const bf16x8 bw =
          *(const bf16x8*)&g_pack[PK_W2 + ((kb * 4 + jb) * 64 + lane) * 8];
      ac2[jb] = mfma16(a, bw, ac2[jb]);
    }
  }
  {
#pragma unroll
    for (int jb = 0; jb < 4; ++jb) {
      const float bb = b2[jb * 16 + lr];
#pragma unroll
      for (int r = 0; r < 4; ++r) {
        const int grow = wv * 16 + q * 4 + r;
        const int col = jb * 16 + lr;
        const float v = fmaxf(ac2[jb][r] + bb, 0.0f);
        const int byte = (grow * 128 + col * 2) ^ ((grow & 7) << 4);
        *(unsigned short*)((char*)sH2 + byte) = f2bf(v);
      }
    }
  }
  __syncthreads();

  f32x4 ac3 = {0, 0, 0, 0};
#pragma unroll
  for (int kb = 0; kb < 2; ++kb) {
    const int byte = (nl * 128 + kb * 64 + q * 16) ^ ((lr & 7) << 4);
    const bf16x8 a = *(const bf16x8*)((const char*)sH2 + byte);
    const bf16x8 bw = *(const bf16x8*)&g_pack[PK_W3 + (kb * 64 + lane) * 8];
    ac3 = mfma16(a, bw, ac3);
  }
  if (lr < 2) {
    const float bb = b3[lr];
#pragma unroll
    for (int r = 0; r < 4; ++r) {
      const int grow = wv * 16 + q * 4 + r;
      const int n = n0 + grow;
      if (n < Nn) out[OFF_PRIORS + ((long)b * Nn + n) * 2 + lr] = ac3[r] + bb;
    }
  }
}

// ---------------- decoder (MFMA) ----------------
__global__ __launch_bounds__(256) void dec_mfma(
    const float* __restrict__ act, const float* __restrict__ b1,
    const float* __restrict__ b2, const float* __restrict__ b3,
    float* __restrict__ out) {
  __shared__ __align__(16) unsigned short sD[64 * 32];
  __shared__ __align__(16) unsigned short sH1[64 * 64];
  __shared__ __align__(16) unsigned short sH2[64 * 64];
  const int b = blockIdx.x >> 3;
  const int n0 = (blockIdx.x & 7) << 6;
  const int tid = threadIdx.x;
  const int lane = tid & 63, wv = tid >> 6;
  const int q = lane >> 4, lr = lane & 15;
  const int nl = wv * 16 + lr;
  const float* posts = out + OFF_POSTS;

  for (int e = tid; e < 64 * 32; e += 256) {
    const int row = e >> 5, c = e & 31;
    int n = n0 + row; n = n < Nn ? n : Nn - 1;
    float v = 0.0f;
    if (c < 2) v = posts[((long)b * Nn + n) * 2 + c];
    else if (c < 10) v = act[((long)b * Tt + n + WL - 1) * AD + c - 2];
    const int byte = (row * 64 + c * 2) ^ ((row & 3) << 4);
    *(unsigned short*)((char*)sD + byte) = f2bf(v);
  }
  __syncthreads();

  f32x4 acc[4] = {{0,0,0,0},{0,0,0,0},{0,0,0,0},{0,0,0,0}};
  {
    const int byte = (nl * 64 + q * 16) ^ ((nl & 3) << 4);
    const bf16x8 a = *(const bf16x8*)((const char*)sD + byte);
#pragma unroll
    for (int jb = 0; jb < 4; ++jb) {
      const bf16x8 bw = *(const bf16x8*)&g_pack[PK_DW1 + (jb * 64 + lane) * 8];
      acc[jb] = mfma16(a, bw, acc[jb]);
    }
  }
  {
#pragma unroll
    for (int jb = 0; jb < 4; ++jb) {
      const float bb = b1[jb * 16 + lr];
#pragma unroll
      for (int r = 0; r < 4; ++r) {
        const int grow = wv * 16 + q * 4 + r;
        const int col = jb * 16 + lr;
        const float v = fmaxf(acc[jb][r] + bb, 0.0f);
        const int byte = (grow * 128 + col * 2) ^ ((grow & 7) << 4);
        *(unsigned short*)((char*)sH1 + byte) = f2bf(v);
      }
    }
  }
  __syncthreads();

  f32x4 ac2[4] = {{0,0,0,0},{0,0,0,0},{0,0,0,0},{0,0,0,0}};
#pragma unroll
  for (int kb = 0; kb < 2; ++kb) {
    const int byte = (nl * 128 + kb * 64 + q * 16) ^ ((lr & 7) << 4);
    const bf16x8 a = *(const bf16x8*)((const char*)sH1 + byte);
#pragma unroll
    for (int jb = 0; jb < 4; ++jb) {
      const bf16x8 bw =
          *(const bf16x8*)&g_pack[PK_DW2 + ((kb * 4 + jb) * 64 + lane) * 8];
      ac2[jb] = mfma16(a, bw, ac2[jb]);
    }
  }
  {
#pragma unroll
    for (int jb = 0; jb < 4; ++jb) {
      const float bb = b2[jb * 16 + lr];
#pragma unroll
      for (int r = 0; r < 4; ++r) {
        const int grow = wv * 16 + q * 4 + r;
        const int col = jb * 16 + lr;
        const float v = fmaxf(ac2[jb][r] + bb, 0.0f);
        const int byte = (grow * 128 + col * 2) ^ ((grow & 7) << 4);
        *(unsigned short*)((char*)sH2 + byte) = f2bf(v);
      }
    }
  }
  __syncthreads();

  f32x4 ac3[2] = {{0,0,0,0},{0,0,0,0}};
#pragma unroll
  for (int kb = 0; kb < 2; ++kb) {
    const int byte = (nl * 128 + kb * 64 + q * 16) ^ ((lr & 7) << 4);
    const bf16x8 a = *(const bf16x8*)((const char*)sH2 + byte);
#pragma unroll
    for (int jb = 0; jb < 2; ++jb) {
      const bf16x8 bw =
          *(const bf16x8*)&g_pack[PK_DW3 + ((kb * 2 + jb) * 64 + lane) * 8];
      ac3[jb] = mfma16(a, bw, ac3[jb]);
    }
  }
#pragma unroll
  for (int jb = 0; jb < 2; ++jb) {
    const int o = jb * 16 + lr;
    const float bb = b3[o];
#pragma unroll
    for (int r = 0; r < 4; ++r) {
      const int grow = wv * 16 + q * 4 + r;
      const int n = n0 + grow;
      if (n < Nn) out[OFF_POST + ((long)b * Nn + n) * 32 + o] = ac3[jb][r] + bb;
    }
  }
}

// ---------------- gprep: fused per-step scan record ----------------
// rec[g][t][0..11] = {gia0..5, pr0, pr1, mfloat, 0, 0, 0}; zero-padded t>=502
__global__ __launch_bounds__(256) void gprep_kernel(
    const float* __restrict__ act, const int* __restrict__ mask,
    const float* __restrict__ Wih, const float* __restrict__ bih,
    const float* __restrict__ out, float* __restrict__ rec) {
  const int idx = blockIdx.x * 256 + threadIdx.x;
  const int total = Bb * REC_T;
  if (idx >= total) return;
  const int g = idx / REC_T;
  const int t = idx - g * REC_T;
  float r[12];
#pragma unroll
  for (int i = 0; i < 12; ++i) r[i] = 0.0f;
  if (t < Nn - 1) {
    const float* a = act + ((long)g * Tt + WL - 1 + t) * AD;
    const float4 a0 = *reinterpret_cast<const float4*>(a);
    const float4 a1 = *reinterpret_cast<const float4*>(a + 4);
#pragma unroll
    for (int q = 0; q < 6; ++q) {
      float acc = bih[q];
      acc = fmaf(a0.x, Wih[0 * 6 + q], acc);
      acc = fmaf(a0.y, Wih[1 * 6 + q], acc);
      acc = fmaf(a0.z, Wih[2 * 6 + q], acc);
      acc = fmaf(a0.w, Wih[3 * 6 + q], acc);
      acc = fmaf(a1.x, Wih[4 * 6 + q], acc);
      acc = fmaf(a1.y, Wih[5 * 6 + q], acc);
      acc = fmaf(a1.z, Wih[6 * 6 + q], acc);
      acc = fmaf(a1.w, Wih[7 * 6 + q], acc);
      r[q] = acc;
    }
    const float2 pr =
        *reinterpret_cast<const float2*>(out + OFF_PRIORS + ((long)g * Nn + t) * 2);
    r[6] = pr.x;
    r[7] = pr.y;
    r[8] = (float)mask[(long)g * Nn + t];
  }
  float4* o = reinterpret_cast<float4*>(rec + (long)idx * 12);
  o[0] = make_float4(r[0], r[1], r[2], r[3]);
  o[1] = make_float4(r[4], r[5], r[6], r[7]);
  o[2] = make_float4(r[8], r[9], r[10], r[11]);
}

// ---------------- scan v3: deep prefetch + DPP butterfly ----------------
// GA = {gia0..3}, GB = {gia4, gia5, pr0, pr1}, MF = mask float
#define SCAN_LOAD(SA, SB, SM, TT)                              \
  do {                                                         \
    const float* p_ = base + (long)(TT) * 12;                  \
    SA = *reinterpret_cast<const float4*>(p_);                 \
    SB = *reinterpret_cast<const float4*>(p_ + 4);             \
    SM = p_[8];                                                \
  } while (0)

#define SCAN_STEP(GA, GB, MF)                                               \
  do {                                                                      \
    const bool mm = ((MF) != 0.0f);                                         \
    const float st0 = mm ? (GB).z : s0p;                                    \
    const float st1 = mm ? (GB).w : s1p;                                    \
    float giq[6], ghq[6];                                                   \
    _Pragma("unroll") for (int q_ = 0; q_ < 6; ++q_) ghq[q_] =              \
        fmaf(x1p, whh1[q_], fmaf(x0p, whh0[q_], bhhv[q_]));                 \
    giq[0] = fmaf(st1, wih9[0], fmaf(st0, wih8[0], (GA).x));                \
    giq[1] = fmaf(st1, wih9[1], fmaf(st0, wih8[1], (GA).y));                \
    giq[2] = fmaf(st1, wih9[2], fmaf(st0, wih8[2], (GA).z));                \
    giq[3] = fmaf(st1, wih9[3], fmaf(st0, wih8[3], (GA).w));                \
    giq[4] = fmaf(st1, wih9[4], fmaf(st0, wih8[4], (GB).x));                \
    giq[5] = fmaf(st1, wih9[5], fmaf(st0, wih8[5], (GB).y));                \
    const float r0 = sigmoidf_(giq[0] + ghq[0]);                            \
    const float r1 = sigmoidf_(giq[1] + ghq[1]);                            \
    const float z0 = sigmoidf_(giq[2] + ghq[2]);                            \
    const float z1 = sigmoidf_(giq[3] + ghq[3]);                            \
    const float nn0 = tanh_(fmaf(r0, ghq[4], giq[4]));                      \
    const float nn1 = tanh_(fmaf(r1, ghq[5], giq[5]));                      \
    const float xn0 = fmaf(z0, x0p - nn0, nn0);                             \
    const float xn1 = fmaf(z1, x1p - nn1, nn1);                             \
    const float h1 = fmaxf(fmaf(xn1, w1c1, fmaf(xn0, w1c0, b1v)), 0.0f);    \
    const float t0 = h1;                                                    \
    const float t1 = dpp_mov<0xB1>(t0);                                     \
    const float t2 = dpp_mov<0x4E>(t0);                                     \
    const float t3 = dpp_mov<0x4E>(t1);                                     \
    const float t4 = dpp_mov<0x141>(t0);                                    \
    const float t5 = dpp_mov<0x141>(t1);                                    \
    const float t6 = dpp_mov<0x141>(t2);                                    \
    const float t7 = dpp_mov<0x141>(t3);                                    \
    const float t8 = dpp_mov<0x128>(t0);                                    \
    const float t9 = dpp_mov<0x128>(t1);                                    \
    const float t10 = dpp_mov<0x128>(t2);                                   \
    const float t11 = dpp_mov<0x128>(t3);                                   \
    const float t12 = dpp_mov<0x128>(t4);                                   \
    const float t13 = dpp_mov<0x128>(t5);                                   \
    const float t14 = dpp_mov<0x128>(t6);                                   \
    const float t15 = dpp_mov<0x128>(t7);                                   \
    float q0 = fmaf(t0, wg[0], b2v);                                        \
    q0 = fmaf(t1, wg[1], q0);                                               \
    q0 = fmaf(t2, wg[2], q0);                                               \
    q0 = fmaf(t3, wg[3], q0);                                               \
    float q1 = t4 * wg[4];                                                  \
    q1 = fmaf(t5, wg[5], q1);                                               \
    q1 = fmaf(t6, wg[6], q1);                                               \
    q1 = fmaf(t7, wg[7], q1);                                               \
    float q2 = t8 * wg[8];                                                  \
    q2 = fmaf(t9, wg[9], q2);                                               \
    q2 = fmaf(t10, wg[10], q2);                                             \
    q2 = fmaf(t11, wg[11], q2);                                             \
    float q3 = t12 * wg[12];                                                \
    q3 = fmaf(t13, wg[13], q3);                                             \
    q3 = fmaf(t14, wg[14], q3);                                             \
    q3 = fmaf(t15, wg[15], q3);                                             \
    const float h2 = fmaxf((q0 + q1) + (q2 + q3), 0.0f);                    \
    float p0 = row16_allsum(h2 * w3a);                                      \
    float p1 = row16_allsum(h2 * w3b);                                      \
    const float sn0 = p0 + b3a;                                             \
    const float sn1 = p1 + b3b;                                             \
    if (lane == 0) *reinterpret_cast<float2*>(xw) = make_float2(xn0, xn1);  \
    if (lane == 1) *reinterpret_cast<float2*>(sw) = make_float2(sn0, sn1);  \
    xw += 2;                                                                \
    sw += 2;                                                                \
    x0p = xn0;                                                              \
    x1p = xn1;                                                              \
    s0p = sn0;                                                              \
    s1p = sn1;                                                              \
  } while (0)

__global__ __launch_bounds__(64) void scan2_kernel(
    const float* __restrict__ rec, const float* __restrict__ pW2,
    const float* __restrict__ pW1, const float* __restrict__ pb1,
    const float* __restrict__ pb2, const float* __restrict__ pW3,
    const float* __restrict__ pb3, const float* __restrict__ Wih,
    const float* __restrict__ Whh, const float* __restrict__ bhh,
    float* __restrict__ out) {
  const int tid = threadIdx.x;
  const int lane = tid & 15;
  const int g = (blockIdx.x * 64 + tid) >> 4;

  float wih8[6], wih9[6], whh0[6], whh1[6], bhhv[6];
#pragma unroll
  for (int q = 0; q < 6; ++q) {
    wih8[q] = Wih[8 * 6 + q];
    wih9[q] = Wih[9 * 6 + q];
    whh0[q] = Whh[q];
    whh1[q] = Whh[6 + q];
    bhhv[q] = bhh[q];
  }
  const float w1c0 = pW1[lane], w1c1 = pW1[16 + lane], b1v = pb1[lane];
  // butterfly-offset-indexed W2: wg[i] = W2[lane ^ otab[i]][lane]
  constexpr int otab[16] = {0, 1, 2, 3, 7, 6, 5, 4, 8, 9, 10, 11, 15, 14, 13, 12};
  float wg[16];
#pragma unroll
  for (int i = 0; i < 16; ++i) wg[i] = pW2[(lane ^ otab[i]) * 16 + lane];
  const float b2v = pb2[lane];
  const float w3a = pW3[lane * 2], w3b = pW3[lane * 2 + 1];
  const float b3a = pb3[0], b3b = pb3[1];

  const float* priors = out + OFF_PRIORS;
  const long pbase = (long)g * Nn;
  const float* base = rec + (long)g * REC_T * 12;
  float* xw = out + OFF_XTRAJ + pbase * 2 + 2;
  float* sw = out + OFF_POSTS + pbase * 2 + 2;

  const float2 s0v = *reinterpret_cast<const float2*>(priors + pbase * 2);
  float x0p = 0.f, x1p = 0.f;
  float s0p = s0v.x, s1p = s0v.y;
  if (lane == 0)
    *reinterpret_cast<float2*>(out + OFF_XTRAJ + pbase * 2) =
        make_float2(0.f, 0.f);
  if (lane == 1)
    *reinterpret_cast<float2*>(out + OFF_POSTS + pbase * 2) =
        make_float2(s0p, s1p);

  float4 A0, A1, A2, A3, A4, A5, A6, A7;
  float4 B0, B1, B2, B3, B4, B5, B6, B7;
  float M0, M1, M2, M3, M4, M5, M6, M7;
  SCAN_LOAD(A0, B0, M0, 0);
  SCAN_LOAD(A1, B1, M1, 1);
  SCAN_LOAD(A2, B2, M2, 2);
  SCAN_LOAD(A3, B3, M3, 3);
  SCAN_LOAD(A4, B4, M4, 4);
  SCAN_LOAD(A5, B5, M5, 5);
  SCAN_LOAD(A6, B6, M6, 6);
  SCAN_LOAD(A7, B7, M7, 7);

  int t = 0;
  // 62*8 = 496 steps in the main loop; 6-step tail => 502 total
  for (int it = 0; it < 62; ++it) {
    SCAN_STEP(A0, B0, M0);
    SCAN_LOAD(A0, B0, M0, t + 8);
    SCAN_STEP(A1, B1, M1);
    SCAN_LOAD(A1, B1, M1, t + 9);
    SCAN_STEP(A2, B2, M2);
    SCAN_LOAD(A2, B2, M2, t + 10);
    SCAN_STEP(A3, B3, M3);
    SCAN_LOAD(A3, B3, M3, t + 11);
    SCAN_STEP(A4, B4, M4);
    SCAN_LOAD(A4, B4, M4, t + 12);
    SCAN_STEP(A5, B5, M5);
    SCAN_LOAD(A5, B5, M5, t + 13);
    SCAN_STEP(A6, B6, M6);
    SCAN_LOAD(A6, B6, M6, t + 14);
    SCAN_STEP(A7, B7, M7);
    SCAN_LOAD(A7, B7, M7, t + 15);
    t += 8;
  }
  SCAN_STEP(A0, B0, M0);
  SCAN_STEP(A1, B1, M1);
  SCAN_STEP(A2, B2, M2);
  SCAN_STEP(A3, B3, M3);
  SCAN_STEP(A4, B4, M4);
  SCAN_STEP(A5, B5, M5);
}

// ---------------- fallback scan (round-3 path, no workspace) ----------------
__global__ __launch_bounds__(64) void scan_fb_kernel(
    const float* __restrict__ act, const int* __restrict__ mask,
    const float* __restrict__ Wih, const float* __restrict__ Whh,
    const float* __restrict__ bih, const float* __restrict__ bhh,
    const float* __restrict__ pW1, const float* __restrict__ pb1,
    const float* __restrict__ pW2, const float* __restrict__ pb2,
    const float* __restrict__ pW3, const float* __restrict__ pb3,
    float* __restrict__ out) {
  const int tid = threadIdx.x;
  const int lane = tid & 15;
  const int g = (blockIdx.x * 64 + tid) >> 4;

  float wih8[6], wih9[6], whh0[6], whh1[6], bhhv[6], bihv[6];
  float wihA[8][6];
#pragma unroll
  for (int q = 0; q < 6; ++q) {
    wih8[q] = Wih[8 * 6 + q];
    wih9[q] = Wih[9 * 6 + q];
    whh0[q] = Whh[q];
    whh1[q] = Whh[6 + q];
    bhhv[q] = bhh[q];
    bihv[q] = bih[q];
  }
#pragma unroll
  for (int i = 0; i < 8; ++i)
#pragma unroll
    for (int q = 0; q < 6; ++q) wihA[i][q] = Wih[i * 6 + q];

  const float w1c0 = pW1[lane], w1c1 = pW1[16 + lane], b1v = pb1[lane];
  float w2c[16];
#pragma unroll
  for (int k = 0; k < 16; ++k) w2c[k] = pW2[k * 16 + lane];
  const float b2v = pb2[lane];
  const float w3a = pW3[lane * 2], w3b = pW3[lane * 2 + 1];
  const float b3a = pb3[0], b3b = pb3[1];

  const float* priors = out + OFF_PRIORS;
  float* posts = out + OFF_POSTS;
  float* xtraj = out + OFF_XTRAJ;
  const long pbase = (long)g * Nn;
  const float* aptr = act + ((long)g * Tt + WL - 1) * 8;

  const float2 s0v = *reinterpret_cast<const float2*>(priors + pbase * 2);
  float x0p = 0.f, x1p = 0.f;
  float s0p = s0v.x, s1p = s0v.y;
  if (lane == 0)
    *reinterpret_cast<float2*>(xtraj + pbase * 2) = make_float2(0.f, 0.f);
  if (lane == 1)
    *reinterpret_cast<float2*>(posts + pbase * 2) = make_float2(s0p, s1p);

  float4 an0 = *reinterpret_cast<const float4*>(aptr);
  float4 an1 = *reinterpret_cast<const float4*>(aptr + 4);
  float2 prn = s0v;
  int mn = mask[pbase];

  for (int t = 0; t < Nn - 1; ++t) {
    const float4 a0 = an0, a1 = an1;
    const float2 pr = prn;
    const int m = mn;
    const int tn1 = (t + 1 < Nn - 1) ? t + 1 : Nn - 2;
    an0 = *reinterpret_cast<const float4*>(aptr + (long)tn1 * 8);
    an1 = *reinterpret_cast<const float4*>(aptr + (long)tn1 * 8 + 4);
    prn = *reinterpret_cast<const float2*>(priors + (pbase + t + 1) * 2);
    mn = mask[pbase + t + 1];

    const float st0 = m ? pr.x : s0p;
    const float st1 = m ? pr.y : s1p;

    float giq[6], ghq[6];
#pragma unroll
    for (int q = 0; q < 6; ++q) {
      float acc = bihv[q];
      acc = fmaf(a0.x, wihA[0][q], acc);
      acc = fmaf(a0.y, wihA[1][q], acc);
      acc = fmaf(a0.z, wihA[2][q], acc);
      acc = fmaf(a0.w, wihA[3][q], acc);
      acc = fmaf(a1.x, wihA[4][q], acc);
      acc = fmaf(a1.y, wihA[5][q], acc);
      acc = fmaf(a1.z, wihA[6][q], acc);
      acc = fmaf(a1.w, wihA[7][q], acc);
      giq[q] = fmaf(st1, wih9[q], fmaf(st0, wih8[q], acc));
      ghq[q] = fmaf(x1p, whh1[q], fmaf(x0p, whh0[q], bhhv[q]));
    }
    const float r0 = sigmoidf_(giq[0] + ghq[0]);
    const float r1 = sigmoidf_(giq[1] + ghq[1]);
    const float z0 = sigmoidf_(giq[2] + ghq[2]);
    const float z1 = sigmoidf_(giq[3] + ghq[3]);
    const float nn0 = tanh_(fmaf(r0, ghq[4], giq[4]));
    const float nn1 = tanh_(fmaf(r1, ghq[5], giq[5]));
    const float xn0 = fmaf(z0, x0p - nn0, nn0);
    const float xn1 = fmaf(z1, x1p - nn1, nn1);

    const float h1 = fmaxf(fmaf(xn1, w1c1, fmaf(xn0, w1c0, b1v)), 0.0f);
    float ha[16];
#pragma unroll
    for (int k = 0; k < 16; ++k) ha[k] = __shfl(h1, k, 16);
    float q0 = fmaf(ha[0], w2c[0], b2v);
    q0 = fmaf(ha[1], w2c[1], q0);
    q0 = fmaf(ha[2], w2c[2], q0);
    q0 = fmaf(ha[3], w2c[3], q0);
    float q1 = ha[4] * w2c[4];
    q1 = fmaf(ha[5], w2c[5], q1);
    q1 = fmaf(ha[6], w2c[6], q1);
    q1 = fmaf(ha[7], w2c[7], q1);
    float q2 = ha[8] * w2c[8];
    q2 = fmaf(ha[9], w2c[9], q2);
    q2 = fmaf(ha[10], w2c[10], q2);
    q2 = fmaf(ha[11], w2c[11], q2);
    float q3 = ha[12] * w2c[12];
    q3 = fmaf(ha[13], w2c[13], q3);
    q3 = fmaf(ha[14], w2c[14], q3);
    q3 = fmaf(ha[15], w2c[15], q3);
    const float h2 = fmaxf((q0 + q1) + (q2 + q3), 0.0f);

    float p0 = row16_allsum(h2 * w3a);
    float p1 = row16_allsum(h2 * w3b);
    const float sn0 = p0 + b3a;
    const float sn1 = p1 + b3b;

    if (lane == 0)
      *reinterpret_cast<float2*>(xtraj + (pbase + t + 1) * 2) =
          make_float2(xn0, xn1);
    if (lane == 1)
      *reinterpret_cast<float2*>(posts + (pbase + t + 1) * 2) =
          make_float2(sn0, sn1);
    x0p = xn0; x1p = xn1; s0p = sn0; s1p = sn1;
  }
}

}  // namespace

extern "C" void kernel_launch(void* const* d_in, const int* in_sizes, int n_in,
                              void* d_out, int out_size, void* d_ws, size_t ws_size,
                              hipStream_t stream) {
  const float* obs    = (const float*)d_in[0];
  const float* action = (const float*)d_in[1];
  const int* t_label  = (const int*)d_in[2];
  const int* mask     = (const int*)d_in[3];
  const float* enc_W1 = (const float*)d_in[4];
  const float* enc_b1 = (const float*)d_in[5];
  const float* enc_W2 = (const float*)d_in[6];
  const float* enc_b2 = (const float*)d_in[7];
  const float* enc_W3 = (const float*)d_in[8];
  const float* enc_b3 = (const float*)d_in[9];
  const float* gru_Wih = (const float*)d_in[10];
  const float* gru_Whh = (const float*)d_in[11];
  const float* gru_bih = (const float*)d_in[12];
  const float* gru_bhh = (const float*)d_in[13];
  const float* post_W1 = (const float*)d_in[14];
  const float* post_b1 = (const float*)d_in[15];
  const float* post_W2 = (const float*)d_in[16];
  const float* post_b2 = (const float*)d_in[17];
  const float* post_W3 = (const float*)d_in[18];
  const float* post_b3 = (const float*)d_in[19];
  const float* dec_W1 = (const float*)d_in[20];
  const float* dec_b1 = (const float*)d_in[21];
  const float* dec_W2 = (const float*)d_in[22];
  const float* dec_b2 = (const float*)d_in[23];
  const float* dec_W3 = (const float*)d_in[24];
  const float* dec_b3 = (const float*)d_in[25];
  float* out = (float*)d_out;

  pack_kernel<<<(PK_TOTAL + 255) / 256, 256, 0, stream>>>(
      enc_W1, enc_W2, enc_W3, dec_W1, dec_W2, dec_W3);

  enc_mfma<<<Bb * 8, 256, 0, stream>>>(obs, action, enc_b1, enc_b2, enc_b3,
                                       out);

  const size_t rec_bytes = (size_t)Bb * REC_T * 12 * sizeof(float);
  if (ws_size >= rec_bytes) {
    float* rec = (float*)d_ws;
    const int total = Bb * REC_T;
    gprep_kernel<<<(total + 255) / 256, 256, 0, stream>>>(
        action, mask, gru_Wih, gru_bih, out, rec);
    scan2_kernel<<<128, 64, 0, stream>>>(rec, post_W2, post_W1, post_b1,
                                         post_b2, post_W3, post_b3, gru_Wih,
                                         gru_Whh, gru_bhh, out);
  } else {
    scan_fb_kernel<<<128, 64, 0, stream>>>(
        action, mask, gru_Wih, gru_Whh, gru_bih, gru_bhh, post_W1, post_b1,
        post_W2, post_b2, post_W3, post_b3, out);
  }

  dec_mfma<<<Bb * 8, 256, 0, stream>>>(action, dec_b1, dec_b2, dec_b3, out);
  copy_kernel<<<2048, 256, 0, stream>>>(obs, t_label, out);
}

// Round 5
// 298.722 us; speedup vs baseline: 2.7272x; 1.0061x over previous
//
#include <hip/hip_runtime.h>
#include <hip/hip_bf16.h>

namespace {

constexpr int Bb = 512;
constexpr int Tt = 512;
constexpr int OD = 32;
constexpr int AD = 8;
constexpr int WL = 10;
constexpr int Nn = Tt - WL + 1;   // 503
constexpr int CH = OD + AD;       // 40
constexpr int REC_T = 504;        // padded step count for scan records

constexpr long SZ_PO = (long)Bb * Nn * 32;
constexpr long SZ_PR = (long)Bb * Nn * 2;
constexpr long OFF_POST   = 0;
constexpr long OFF_PRIORS = SZ_PO;
constexpr long OFF_POSTS  = OFF_PRIORS + SZ_PR;
constexpr long OFF_XTRAJ  = OFF_POSTS + SZ_PR;
constexpr long OFF_TGT    = OFF_XTRAJ + SZ_PR;
constexpr long OFF_LAB    = OFF_TGT + SZ_PO;

// ---- packed weight buffer (bf16 MFMA B-fragments), device-global ----
constexpr int PK_W1  = 0;              // 13 kb x 4 jb
constexpr int PK_W2  = 26624;          // 2 x 4
constexpr int PK_W3  = 30720;          // 2 x 1
constexpr int PK_DW1 = 31744;          // 1 x 4
constexpr int PK_DW2 = 33792;          // 2 x 4
constexpr int PK_DW3 = 37888;          // 2 x 2
constexpr int PK_TOTAL = 39936;

typedef __attribute__((ext_vector_type(8))) short bf16x8;
typedef __attribute__((ext_vector_type(4))) float f32x4;

__device__ __align__(16) short g_pack[PK_TOTAL];

__device__ __forceinline__ f32x4 mfma16(bf16x8 a, bf16x8 b, f32x4 c) {
  return __builtin_amdgcn_mfma_f32_16x16x32_bf16(a, b, c, 0, 0, 0);
}

__device__ __forceinline__ unsigned short f2bf(float x) {
  unsigned int u = __float_as_uint(x);
  unsigned int r = u + 0x7fffu + ((u >> 16) & 1u);
  return (unsigned short)(r >> 16);
}

__device__ __forceinline__ float sigmoidf_(float x) {
  return 1.0f / (1.0f + __expf(-x));
}
__device__ __forceinline__ float tanh_(float x) {
  return 1.0f - 2.0f / (__expf(2.0f * x) + 1.0f);
}

template <int CTRL>
__device__ __forceinline__ float dpp_add(float x) {
  int y = __builtin_amdgcn_update_dpp(0, __float_as_int(x), CTRL, 0xf, 0xf, false);
  return x + __int_as_float(y);
}
template <int CTRL>
__device__ __forceinline__ float dpp_mov(float x) {
  return __int_as_float(
      __builtin_amdgcn_update_dpp(0, __float_as_int(x), CTRL, 0xf, 0xf, false));
}
__device__ __forceinline__ float row16_allsum(float x) {
  x = dpp_add<0xB1>(x);   // xor 1
  x = dpp_add<0x4E>(x);   // xor 2
  x = dpp_add<0x141>(x);  // xor 7 (row_half_mirror)
  x = dpp_add<0x140>(x);  // xor 15 (row_mirror)
  return x;
}

// ---------------- weight prepack ----------------
__global__ __launch_bounds__(256) void pack_kernel(
    const float* __restrict__ W1, const float* __restrict__ W2,
    const float* __restrict__ W3, const float* __restrict__ dW1,
    const float* __restrict__ dW2, const float* __restrict__ dW3) {
  const int idx = blockIdx.x * 256 + threadIdx.x;
  if (idx >= PK_TOTAL) return;
  float v = 0.0f;
  int base, r;
  if (idx < PK_W2) {
    base = PK_W1; r = idx - base;
    const int frag = r >> 9, inner = r & 511;
    const int lane = inner >> 3, j = inner & 7;
    const int kb = frag >> 2, jb = frag & 3;
    const int col = lane & 15;
    const int kp = kb * 32 + ((lane >> 4) << 3) + j;
    if (kp < 400) {
      const int w = kp / 40, c = kp - w * 40;
      v = W1[(c * 10 + w) * 64 + jb * 16 + col];
    }
  } else if (idx < PK_W3) {
    base = PK_W2; r = idx - base;
    const int frag = r >> 9, inner = r & 511;
    const int lane = inner >> 3, j = inner & 7;
    const int kb = frag >> 2, jb = frag & 3;
    const int col = lane & 15;
    const int k = kb * 32 + ((lane >> 4) << 3) + j;
    v = W2[k * 64 + jb * 16 + col];
  } else if (idx < PK_DW1) {
    base = PK_W3; r = idx - base;
    const int frag = r >> 9, inner = r & 511;
    const int lane = inner >> 3, j = inner & 7;
    const int kb = frag;
    const int col = lane & 15;
    const int k = kb * 32 + ((lane >> 4) << 3) + j;
    v = (col < 2) ? W3[k * 2 + col] : 0.0f;
  } else if (idx < PK_DW2) {
    base = PK_DW1; r = idx - base;
    const int frag = r >> 9, inner = r & 511;
    const int lane = inner >> 3, j = inner & 7;
    const int jb = frag;
    const int col = lane & 15;
    const int k = ((lane >> 4) << 3) + j;
    v = (k < 10) ? dW1[k * 64 + jb * 16 + col] : 0.0f;
  } else if (idx < PK_DW3) {
    base = PK_DW2; r = idx - base;
    const int frag = r >> 9, inner = r & 511;
    const int lane = inner >> 3, j = inner & 7;
    const int kb = frag >> 2, jb = frag & 3;
    const int col = lane & 15;
    const int k = kb * 32 + ((lane >> 4) << 3) + j;
    v = dW2[k * 64 + jb * 16 + col];
  } else {
    base = PK_DW3; r = idx - base;
    const int frag = r >> 9, inner = r & 511;
    const int lane = inner >> 3, j = inner & 7;
    const int kb = frag >> 1, jb = frag & 1;
    const int col = lane & 15;
    const int k = kb * 32 + ((lane >> 4) << 3) + j;
    v = dW3[k * 32 + jb * 16 + col];
  }
  g_pack[idx] = (short)f2bf(v);
}

// ---------------- copies ----------------
__global__ void copy_kernel(const float* __restrict__ obs,
                            const int* __restrict__ tlab,
                            float* __restrict__ out) {
  const int total4 = (int)(SZ_PO / 4);
  const int totalL = Bb * Nn;
  const int stride = gridDim.x * blockDim.x;
  float4* out4 = reinterpret_cast<float4*>(out + OFF_TGT);
  const float4* obs4 = reinterpret_cast<const float4*>(obs);
  for (int idx = blockIdx.x * blockDim.x + threadIdx.x;
       idx < total4 + totalL; idx += stride) {
    if (idx < total4) {
      const int b = idx / (Nn * 8);
      const int r = idx - b * (Nn * 8);
      const int n = r >> 3;
      const int c4 = r & 7;
      out4[idx] = obs4[((long)b * Tt + n + WL - 1) * 8 + c4];
    } else {
      const int j = idx - total4;
      const int b = j / Nn;
      const int n = j - b * Nn;
      out[OFF_LAB + j] = (float)tlab[(long)b * Tt + n + WL - 1];
    }
  }
}

// ---------------- encoder (MFMA) ----------------
__global__ __launch_bounds__(256) void enc_mfma(
    const float* __restrict__ obs, const float* __restrict__ act,
    const float* __restrict__ b1, const float* __restrict__ b2,
    const float* __restrict__ b3, float* __restrict__ out) {
  __shared__ __align__(16) unsigned short sA[74 * 40];
  __shared__ __align__(16) unsigned short sH1[64 * 64];
  __shared__ __align__(16) unsigned short sH2[64 * 64];
  const int b = blockIdx.x >> 3;
  const int n0 = (blockIdx.x & 7) << 6;
  const int tid = threadIdx.x;
  const int lane = tid & 63, wv = tid >> 6;
  const int q = lane >> 4, lr = lane & 15;
  const int nl = wv * 16 + lr;

  for (int e = tid; e < 74 * 40; e += 256) {
    const int row = e / 40, c = e - row * 40;
    int t = n0 + row; t = t < Tt ? t : Tt - 1;
    const float v = (c < OD) ? obs[((long)b * Tt + t) * OD + c]
                             : act[((long)b * Tt + t) * AD + c - OD];
    sA[e] = f2bf(v);
  }
  __syncthreads();

  const char* sAb = (const char*)sA;
  f32x4 acc[4] = {{0,0,0,0},{0,0,0,0},{0,0,0,0},{0,0,0,0}};
  {
    int c0 = q * 8, w = 0;
#pragma unroll
    for (int kb = 0; kb < 13; ++kb) {
      const bf16x8 a = *(const bf16x8*)(sAb + (nl + w) * 80 + c0 * 2);
#pragma unroll
      for (int jb = 0; jb < 4; ++jb) {
        const bf16x8 bw =
            *(const bf16x8*)&g_pack[PK_W1 + ((kb * 4 + jb) * 64 + lane) * 8];
        acc[jb] = mfma16(a, bw, acc[jb]);
      }
      c0 += 32;
      if (c0 >= 40) { c0 -= 40; ++w; }
    }
  }
  {
#pragma unroll
    for (int jb = 0; jb < 4; ++jb) {
      const float bb = b1[jb * 16 + lr];
#pragma unroll
      for (int r = 0; r < 4; ++r) {
        const int grow = wv * 16 + q * 4 + r;
        const int col = jb * 16 + lr;
        const float v = fmaxf(acc[jb][r] + bb, 0.0f);
        const int byte = (grow * 128 + col * 2) ^ ((grow & 7) << 4);
        *(unsigned short*)((char*)sH1 + byte) = f2bf(v);
      }
    }
  }
  __syncthreads();

  f32x4 ac2[4] = {{0,0,0,0},{0,0,0,0},{0,0,0,0},{0,0,0,0}};
#pragma unroll
  for (int kb = 0; kb < 2; ++kb) {
    const int byte = (nl * 128 + kb * 64 + q * 16) ^ ((lr & 7) << 4);
    const bf16x8 a = *(const bf16x8*)((const char*)sH1 + byte);
#pragma unroll
    for (int jb = 0; jb < 4; ++jb) {
      const bf16x8 bw =
          *(const bf16x8*)&g_pack[PK_W2 + ((kb * 4 + jb) * 64 + lane) * 8];
      ac2[jb] = mfma16(a, bw, ac2[jb]);
    }
  }
  {
#pragma unroll
    for (int jb = 0; jb < 4; ++jb) {
      const float bb = b2[jb * 16 + lr];
#pragma unroll
      for (int r = 0; r < 4; ++r) {
        const int grow = wv * 16 + q * 4 + r;
        const int col = jb * 16 + lr;
        const float v = fmaxf(ac2[jb][r] + bb, 0.0f);
        const int byte = (grow * 128 + col * 2) ^ ((grow & 7) << 4);
        *(unsigned short*)((char*)sH2 + byte) = f2bf(v);
      }
    }
  }
  __syncthreads();

  f32x4 ac3 = {0, 0, 0, 0};
#pragma unroll
  for (int kb = 0; kb < 2; ++kb) {
    const int byte = (nl * 128 + kb * 64 + q * 16) ^ ((lr & 7) << 4);
    const bf16x8 a = *(const bf16x8*)((const char*)sH2 + byte);
    const bf16x8 bw = *(const bf16x8*)&g_pack[PK_W3 + (kb * 64 + lane) * 8];
    ac3 = mfma16(a, bw, ac3);
  }
  if (lr < 2) {
    const float bb = b3[lr];
#pragma unroll
    for (int r = 0; r < 4; ++r) {
      const int grow = wv * 16 + q * 4 + r;
      const int n = n0 + grow;
      if (n < Nn) out[OFF_PRIORS + ((long)b * Nn + n) * 2 + lr] = ac3[r] + bb;
    }
  }
}

// ---------------- decoder (MFMA) ----------------
__global__ __launch_bounds__(256) void dec_mfma(
    const float* __restrict__ act, const float* __restrict__ b1,
    const float* __restrict__ b2, const float* __restrict__ b3,
    float* __restrict__ out) {
  __shared__ __align__(16) unsigned short sD[64 * 32];
  __shared__ __align__(16) unsigned short sH1[64 * 64];
  __shared__ __align__(16) unsigned short sH2[64 * 64];
  const int b = blockIdx.x >> 3;
  const int n0 = (blockIdx.x & 7) << 6;
  const int tid = threadIdx.x;
  const int lane = tid & 63, wv = tid >> 6;
  const int q = lane >> 4, lr = lane & 15;
  const int nl = wv * 16 + lr;
  const float* posts = out + OFF_POSTS;

  for (int e = tid; e < 64 * 32; e += 256) {
    const int row = e >> 5, c = e & 31;
    int n = n0 + row; n = n < Nn ? n : Nn - 1;
    float v = 0.0f;
    if (c < 2) v = posts[((long)b * Nn + n) * 2 + c];
    else if (c < 10) v = act[((long)b * Tt + n + WL - 1) * AD + c - 2];
    const int byte = (row * 64 + c * 2) ^ ((row & 3) << 4);
    *(unsigned short*)((char*)sD + byte) = f2bf(v);
  }
  __syncthreads();

  f32x4 acc[4] = {{0,0,0,0},{0,0,0,0},{0,0,0,0},{0,0,0,0}};
  {
    const int byte = (nl * 64 + q * 16) ^ ((nl & 3) << 4);
    const bf16x8 a = *(const bf16x8*)((const char*)sD + byte);
#pragma unroll
    for (int jb = 0; jb < 4; ++jb) {
      const bf16x8 bw = *(const bf16x8*)&g_pack[PK_DW1 + (jb * 64 + lane) * 8];
      acc[jb] = mfma16(a, bw, acc[jb]);
    }
  }
  {
#pragma unroll
    for (int jb = 0; jb < 4; ++jb) {
      const float bb = b1[jb * 16 + lr];
#pragma unroll
      for (int r = 0; r < 4; ++r) {
        const int grow = wv * 16 + q * 4 + r;
        const int col = jb * 16 + lr;
        const float v = fmaxf(acc[jb][r] + bb, 0.0f);
        const int byte = (grow * 128 + col * 2) ^ ((grow & 7) << 4);
        *(unsigned short*)((char*)sH1 + byte) = f2bf(v);
      }
    }
  }
  __syncthreads();

  f32x4 ac2[4] = {{0,0,0,0},{0,0,0,0},{0,0,0,0},{0,0,0,0}};
#pragma unroll
  for (int kb = 0; kb < 2; ++kb) {
    const int byte = (nl * 128 + kb * 64 + q * 16) ^ ((lr & 7) << 4);
    const bf16x8 a = *(const bf16x8*)((const char*)sH1 + byte);
#pragma unroll
    for (int jb = 0; jb < 4; ++jb) {
      const bf16x8 bw =
          *(const bf16x8*)&g_pack[PK_DW2 + ((kb * 4 + jb) * 64 + lane) * 8];
      ac2[jb] = mfma16(a, bw, ac2[jb]);
    }
  }
  {
#pragma unroll
    for (int jb = 0; jb < 4; ++jb) {
      const float bb = b2[jb * 16 + lr];
#pragma unroll
      for (int r = 0; r < 4; ++r) {
        const int grow = wv * 16 + q * 4 + r;
        const int col = jb * 16 + lr;
        const float v = fmaxf(ac2[jb][r] + bb, 0.0f);
        const int byte = (grow * 128 + col * 2) ^ ((grow & 7) << 4);
        *(unsigned short*)((char*)sH2 + byte) = f2bf(v);
      }
    }
  }
  __syncthreads();

  f32x4 ac3[2] = {{0,0,0,0},{0,0,0,0}};
#pragma unroll
  for (int kb = 0; kb < 2; ++kb) {
    const int byte = (nl * 128 + kb * 64 + q * 16) ^ ((lr & 7) << 4);
    const bf16x8 a = *(const bf16x8*)((const char*)sH2 + byte);
#pragma unroll
    for (int jb = 0; jb < 2; ++jb) {
      const bf16x8 bw =
          *(const bf16x8*)&g_pack[PK_DW3 + ((kb * 2 + jb) * 64 + lane) * 8];
      ac3[jb] = mfma16(a, bw, ac3[jb]);
    }
  }
#pragma unroll
  for (int jb = 0; jb < 2; ++jb) {
    const int o = jb * 16 + lr;
    const float bb = b3[o];
#pragma unroll
    for (int r = 0; r < 4; ++r) {
      const int grow = wv * 16 + q * 4 + r;
      const int n = n0 + grow;
      if (n < Nn) out[OFF_POST + ((long)b * Nn + n) * 32 + o] = ac3[jb][r] + bb;
    }
  }
}

// ---------------- gprep: fused per-step scan record ----------------
__global__ __launch_bounds__(256) void gprep_kernel(
    const float* __restrict__ act, const int* __restrict__ mask,
    const float* __restrict__ Wih, const float* __restrict__ bih,
    const float* __restrict__ out, float* __restrict__ rec) {
  const int idx = blockIdx.x * 256 + threadIdx.x;
  const int total = Bb * REC_T;
  if (idx >= total) return;
  const int g = idx / REC_T;
  const int t = idx - g * REC_T;
  float r[12];
#pragma unroll
  for (int i = 0; i < 12; ++i) r[i] = 0.0f;
  if (t < Nn - 1) {
    const float* a = act + ((long)g * Tt + WL - 1 + t) * AD;
    const float4 a0 = *reinterpret_cast<const float4*>(a);
    const float4 a1 = *reinterpret_cast<const float4*>(a + 4);
#pragma unroll
    for (int q = 0; q < 6; ++q) {
      float acc = bih[q];
      acc = fmaf(a0.x, Wih[0 * 6 + q], acc);
      acc = fmaf(a0.y, Wih[1 * 6 + q], acc);
      acc = fmaf(a0.z, Wih[2 * 6 + q], acc);
      acc = fmaf(a0.w, Wih[3 * 6 + q], acc);
      acc = fmaf(a1.x, Wih[4 * 6 + q], acc);
      acc = fmaf(a1.y, Wih[5 * 6 + q], acc);
      acc = fmaf(a1.z, Wih[6 * 6 + q], acc);
      acc = fmaf(a1.w, Wih[7 * 6 + q], acc);
      r[q] = acc;
    }
    const float2 pr =
        *reinterpret_cast<const float2*>(out + OFF_PRIORS + ((long)g * Nn + t) * 2);
    r[6] = pr.x;
    r[7] = pr.y;
    r[8] = (float)mask[(long)g * Nn + t];
  }
  float4* o = reinterpret_cast<float4*>(rec + (long)idx * 12);
  o[0] = make_float4(r[0], r[1], r[2], r[3]);
  o[1] = make_float4(r[4], r[5], r[6], r[7]);
  o[2] = make_float4(r[8], r[9], r[10], r[11]);
}

// ---------------- scan v4: PINNED deep prefetch + DPP butterfly ----------------
#define SB() __builtin_amdgcn_sched_barrier(0)

#define SCAN_LOAD(SA, SB_, SM, TT)                             \
  do {                                                         \
    const float* p_ = base + (long)(TT) * 12;                  \
    SA = *reinterpret_cast<const float4*>(p_);                 \
    SB_ = *reinterpret_cast<const float4*>(p_ + 4);            \
    SM = p_[8];                                                \
  } while (0)

#define SCAN_STEP(GA, GB, MF)                                               \
  do {                                                                      \
    const bool mm = ((MF) != 0.0f);                                         \
    const float st0 = mm ? (GB).z : s0p;                                    \
    const float st1 = mm ? (GB).w : s1p;                                    \
    float giq[6], ghq[6];                                                   \
    _Pragma("unroll") for (int q_ = 0; q_ < 6; ++q_) ghq[q_] =              \
        fmaf(x1p, whh1[q_], fmaf(x0p, whh0[q_], bhhv[q_]));                 \
    giq[0] = fmaf(st1, wih9[0], fmaf(st0, wih8[0], (GA).x));                \
    giq[1] = fmaf(st1, wih9[1], fmaf(st0, wih8[1], (GA).y));                \
    giq[2] = fmaf(st1, wih9[2], fmaf(st0, wih8[2], (GA).z));                \
    giq[3] = fmaf(st1, wih9[3], fmaf(st0, wih8[3], (GA).w));                \
    giq[4] = fmaf(st1, wih9[4], fmaf(st0, wih8[4], (GB).x));                \
    giq[5] = fmaf(st1, wih9[5], fmaf(st0, wih8[5], (GB).y));                \
    const float r0 = sigmoidf_(giq[0] + ghq[0]);                            \
    const float r1 = sigmoidf_(giq[1] + ghq[1]);                            \
    const float z0 = sigmoidf_(giq[2] + ghq[2]);                            \
    const float z1 = sigmoidf_(giq[3] + ghq[3]);                            \
    const float nn0 = tanh_(fmaf(r0, ghq[4], giq[4]));                      \
    const float nn1 = tanh_(fmaf(r1, ghq[5], giq[5]));                      \
    const float xn0 = fmaf(z0, x0p - nn0, nn0);                             \
    const float xn1 = fmaf(z1, x1p - nn1, nn1);                             \
    const float h1 = fmaxf(fmaf(xn1, w1c1, fmaf(xn0, w1c0, b1v)), 0.0f);    \
    const float t0 = h1;                                                    \
    const float t1 = dpp_mov<0xB1>(t0);                                     \
    const float t2 = dpp_mov<0x4E>(t0);                                     \
    const float t3 = dpp_mov<0x4E>(t1);                                     \
    const float t4 = dpp_mov<0x141>(t0);                                    \
    const float t5 = dpp_mov<0x141>(t1);                                    \
    const float t6 = dpp_mov<0x141>(t2);                                    \
    const float t7 = dpp_mov<0x141>(t3);                                    \
    const float t8 = dpp_mov<0x128>(t0);                                    \
    const float t9 = dpp_mov<0x128>(t1);                                    \
    const float t10 = dpp_mov<0x128>(t2);                                   \
    const float t11 = dpp_mov<0x128>(t3);                                   \
    const float t12 = dpp_mov<0x128>(t4);                                   \
    const float t13 = dpp_mov<0x128>(t5);                                   \
    const float t14 = dpp_mov<0x128>(t6);                                   \
    const float t15 = dpp_mov<0x128>(t7);                                   \
    float q0 = fmaf(t0, wg[0], b2v);                                        \
    q0 = fmaf(t1, wg[1], q0);                                               \
    q0 = fmaf(t2, wg[2], q0);                                               \
    q0 = fmaf(t3, wg[3], q0);                                               \
    float q1 = t4 * wg[4];                                                  \
    q1 = fmaf(t5, wg[5], q1);                                               \
    q1 = fmaf(t6, wg[6], q1);                                               \
    q1 = fmaf(t7, wg[7], q1);                                               \
    float q2 = t8 * wg[8];                                                  \
    q2 = fmaf(t9, wg[9], q2);                                               \
    q2 = fmaf(t10, wg[10], q2);                                             \
    q2 = fmaf(t11, wg[11], q2);                                             \
    float q3 = t12 * wg[12];                                                \
    q3 = fmaf(t13, wg[13], q3);                                             \
    q3 = fmaf(t14, wg[14], q3);                                             \
    q3 = fmaf(t15, wg[15], q3);                                             \
    const float h2 = fmaxf((q0 + q1) + (q2 + q3), 0.0f);                    \
    float p0 = row16_allsum(h2 * w3a);                                      \
    float p1 = row16_allsum(h2 * w3b);                                      \
    const float sn0 = p0 + b3a;                                             \
    const float sn1 = p1 + b3b;                                             \
    if (lane == 0) *reinterpret_cast<float2*>(xw) = make_float2(xn0, xn1);  \
    if (lane == 1) *reinterpret_cast<float2*>(sw) = make_float2(sn0, sn1);  \
    xw += 2;                                                                \
    sw += 2;                                                                \
    x0p = xn0;                                                              \
    x1p = xn1;                                                              \
    s0p = sn0;                                                              \
    s1p = sn1;                                                              \
  } while (0)

__global__ __launch_bounds__(64, 1) void scan2_kernel(
    const float* __restrict__ rec, const float* __restrict__ pW2,
    const float* __restrict__ pW1, const float* __restrict__ pb1,
    const float* __restrict__ pb2, const float* __restrict__ pW3,
    const float* __restrict__ pb3, const float* __restrict__ Wih,
    const float* __restrict__ Whh, const float* __restrict__ bhh,
    float* __restrict__ out) {
  const int tid = threadIdx.x;
  const int lane = tid & 15;
  const int g = (blockIdx.x * 64 + tid) >> 4;

  float wih8[6], wih9[6], whh0[6], whh1[6], bhhv[6];
#pragma unroll
  for (int q = 0; q < 6; ++q) {
    wih8[q] = Wih[8 * 6 + q];
    wih9[q] = Wih[9 * 6 + q];
    whh0[q] = Whh[q];
    whh1[q] = Whh[6 + q];
    bhhv[q] = bhh[q];
  }
  const float w1c0 = pW1[lane], w1c1 = pW1[16 + lane], b1v = pb1[lane];
  constexpr int otab[16] = {0, 1, 2, 3, 7, 6, 5, 4, 8, 9, 10, 11, 15, 14, 13, 12};
  float wg[16];
#pragma unroll
  for (int i = 0; i < 16; ++i) wg[i] = pW2[(lane ^ otab[i]) * 16 + lane];
  const float b2v = pb2[lane];
  const float w3a = pW3[lane * 2], w3b = pW3[lane * 2 + 1];
  const float b3a = pb3[0], b3b = pb3[1];

  const float* priors = out + OFF_PRIORS;
  const long pbase = (long)g * Nn;
  const float* base = rec + (long)g * REC_T * 12;
  float* xw = out + OFF_XTRAJ + pbase * 2 + 2;
  float* sw = out + OFF_POSTS + pbase * 2 + 2;

  const float2 s0v = *reinterpret_cast<const float2*>(priors + pbase * 2);
  float x0p = 0.f, x1p = 0.f;
  float s0p = s0v.x, s1p = s0v.y;
  if (lane == 0)
    *reinterpret_cast<float2*>(out + OFF_XTRAJ + pbase * 2) =
        make_float2(0.f, 0.f);
  if (lane == 1)
    *reinterpret_cast<float2*>(out + OFF_POSTS + pbase * 2) =
        make_float2(s0p, s1p);

  float4 A0, A1, A2, A3, A4, A5, A6, A7;
  float4 B0, B1, B2, B3, B4, B5, B6, B7;
  float M0, M1, M2, M3, M4, M5, M6, M7;
  SCAN_LOAD(A0, B0, M0, 0);
  SCAN_LOAD(A1, B1, M1, 1);
  SCAN_LOAD(A2, B2, M2, 2);
  SCAN_LOAD(A3, B3, M3, 3);
  SCAN_LOAD(A4, B4, M4, 4);
  SCAN_LOAD(A5, B5, M5, 5);
  SCAN_LOAD(A6, B6, M6, 6);
  SCAN_LOAD(A7, B7, M7, 7);
  SB();

  int t = 0;
  // 62*8 = 496 steps in the main loop; 6-step tail => 502 total
  for (int it = 0; it < 62; ++it) {
    SCAN_STEP(A0, B0, M0);
    SCAN_LOAD(A0, B0, M0, t + 8);
    SB();
    SCAN_STEP(A1, B1, M1);
    SCAN_LOAD(A1, B1, M1, t + 9);
    SB();
    SCAN_STEP(A2, B2, M2);
    SCAN_LOAD(A2, B2, M2, t + 10);
    SB();
    SCAN_STEP(A3, B3, M3);
    SCAN_LOAD(A3, B3, M3, t + 11);
    SB();
    SCAN_STEP(A4, B4, M4);
    SCAN_LOAD(A4, B4, M4, t + 12);
    SB();
    SCAN_STEP(A5, B5, M5);
    SCAN_LOAD(A5, B5, M5, t + 13);
    SB();
    SCAN_STEP(A6, B6, M6);
    SCAN_LOAD(A6, B6, M6, t + 14);
    SB();
    SCAN_STEP(A7, B7, M7);
    SCAN_LOAD(A7, B7, M7, t + 15);
    SB();
    t += 8;
  }
  SCAN_STEP(A0, B0, M0);
  SCAN_STEP(A1, B1, M1);
  SCAN_STEP(A2, B2, M2);
  SCAN_STEP(A3, B3, M3);
  SCAN_STEP(A4, B4, M4);
  SCAN_STEP(A5, B5, M5);
}

// ---------------- fallback scan (no workspace) ----------------
__global__ __launch_bounds__(64) void scan_fb_kernel(
    const float* __restrict__ act, const int* __restrict__ mask,
    const float* __restrict__ Wih, const float* __restrict__ Whh,
    const float* __restrict__ bih, const float* __restrict__ bhh,
    const float* __restrict__ pW1, const float* __restrict__ pb1,
    const float* __restrict__ pW2, const float* __restrict__ pb2,
    const float* __restrict__ pW3, const float* __restrict__ pb3,
    float* __restrict__ out) {
  const int tid = threadIdx.x;
  const int lane = tid & 15;
  const int g = (blockIdx.x * 64 + tid) >> 4;

  float wih8[6], wih9[6], whh0[6], whh1[6], bhhv[6], bihv[6];
  float wihA[8][6];
#pragma unroll
  for (int q = 0; q < 6; ++q) {
    wih8[q] = Wih[8 * 6 + q];
    wih9[q] = Wih[9 * 6 + q];
    whh0[q] = Whh[q];
    whh1[q] = Whh[6 + q];
    bhhv[q] = bhh[q];
    bihv[q] = bih[q];
  }
#pragma unroll
  for (int i = 0; i < 8; ++i)
#pragma unroll
    for (int q = 0; q < 6; ++q) wihA[i][q] = Wih[i * 6 + q];

  const float w1c0 = pW1[lane], w1c1 = pW1[16 + lane], b1v = pb1[lane];
  float w2c[16];
#pragma unroll
  for (int k = 0; k < 16; ++k) w2c[k] = pW2[k * 16 + lane];
  const float b2v = pb2[lane];
  const float w3a = pW3[lane * 2], w3b = pW3[lane * 2 + 1];
  const float b3a = pb3[0], b3b = pb3[1];

  const float* priors = out + OFF_PRIORS;
  float* posts = out + OFF_POSTS;
  float* xtraj = out + OFF_XTRAJ;
  const long pbase = (long)g * Nn;
  const float* aptr = act + ((long)g * Tt + WL - 1) * 8;

  const float2 s0v = *reinterpret_cast<const float2*>(priors + pbase * 2);
  float x0p = 0.f, x1p = 0.f;
  float s0p = s0v.x, s1p = s0v.y;
  if (lane == 0)
    *reinterpret_cast<float2*>(xtraj + pbase * 2) = make_float2(0.f, 0.f);
  if (lane == 1)
    *reinterpret_cast<float2*>(posts + pbase * 2) = make_float2(s0p, s1p);

  float4 an0 = *reinterpret_cast<const float4*>(aptr);
  float4 an1 = *reinterpret_cast<const float4*>(aptr + 4);
  float2 prn = s0v;
  int mn = mask[pbase];

  for (int t = 0; t < Nn - 1; ++t) {
    const float4 a0 = an0, a1 = an1;
    const float2 pr = prn;
    const int m = mn;
    const int tn1 = (t + 1 < Nn - 1) ? t + 1 : Nn - 2;
    an0 = *reinterpret_cast<const float4*>(aptr + (long)tn1 * 8);
    an1 = *reinterpret_cast<const float4*>(aptr + (long)tn1 * 8 + 4);
    prn = *reinterpret_cast<const float2*>(priors + (pbase + t + 1) * 2);
    mn = mask[pbase + t + 1];

    const float st0 = m ? pr.x : s0p;
    const float st1 = m ? pr.y : s1p;

    float giq[6], ghq[6];
#pragma unroll
    for (int q = 0; q < 6; ++q) {
      float acc = bihv[q];
      acc = fmaf(a0.x, wihA[0][q], acc);
      acc = fmaf(a0.y, wihA[1][q], acc);
      acc = fmaf(a0.z, wihA[2][q], acc);
      acc = fmaf(a0.w, wihA[3][q], acc);
      acc = fmaf(a1.x, wihA[4][q], acc);
      acc = fmaf(a1.y, wihA[5][q], acc);
      acc = fmaf(a1.z, wihA[6][q], acc);
      acc = fmaf(a1.w, wihA[7][q], acc);
      giq[q] = fmaf(st1, wih9[q], fmaf(st0, wih8[q], acc));
      ghq[q] = fmaf(x1p, whh1[q], fmaf(x0p, whh0[q], bhhv[q]));
    }
    const float r0 = sigmoidf_(giq[0] + ghq[0]);
    const float r1 = sigmoidf_(giq[1] + ghq[1]);
    const float z0 = sigmoidf_(giq[2] + ghq[2]);
    const float z1 = sigmoidf_(giq[3] + ghq[3]);
    const float nn0 = tanh_(fmaf(r0, ghq[4], giq[4]));
    const float nn1 = tanh_(fmaf(r1, ghq[5], giq[5]));
    const float xn0 = fmaf(z0, x0p - nn0, nn0);
    const float xn1 = fmaf(z1, x1p - nn1, nn1);

    const float h1 = fmaxf(fmaf(xn1, w1c1, fmaf(xn0, w1c0, b1v)), 0.0f);
    float ha[16];
#pragma unroll
    for (int k = 0; k < 16; ++k) ha[k] = __shfl(h1, k, 16);
    float q0 = fmaf(ha[0], w2c[0], b2v);
    q0 = fmaf(ha[1], w2c[1], q0);
    q0 = fmaf(ha[2], w2c[2], q0);
    q0 = fmaf(ha[3], w2c[3], q0);
    float q1 = ha[4] * w2c[4];
    q1 = fmaf(ha[5], w2c[5], q1);
    q1 = fmaf(ha[6], w2c[6], q1);
    q1 = fmaf(ha[7], w2c[7], q1);
    float q2 = ha[8] * w2c[8];
    q2 = fmaf(ha[9], w2c[9], q2);
    q2 = fmaf(ha[10], w2c[10], q2);
    q2 = fmaf(ha[11], w2c[11], q2);
    float q3 = ha[12] * w2c[12];
    q3 = fmaf(ha[13], w2c[13], q3);
    q3 = fmaf(ha[14], w2c[14], q3);
    q3 = fmaf(ha[15], w2c[15], q3);
    const float h2 = fmaxf((q0 + q1) + (q2 + q3), 0.0f);

    float p0 = row16_allsum(h2 * w3a);
    float p1 = row16_allsum(h2 * w3b);
    const float sn0 = p0 + b3a;
    const float sn1 = p1 + b3b;

    if (lane == 0)
      *reinterpret_cast<float2*>(xtraj + (pbase + t + 1) * 2) =
          make_float2(xn0, xn1);
    if (lane == 1)
      *reinterpret_cast<float2*>(posts + (pbase + t + 1) * 2) =
          make_float2(sn0, sn1);
    x0p = xn0; x1p = xn1; s0p = sn0; s1p = sn1;
  }
}

}  // namespace

extern "C" void kernel_launch(void* const* d_in, const int* in_sizes, int n_in,
                              void* d_out, int out_size, void* d_ws, size_t ws_size,
                              hipStream_t stream) {
  const float* obs    = (const float*)d_in[0];
  const float* action = (const float*)d_in[1];
  const int* t_label  = (const int*)d_in[2];
  const int* mask     = (const int*)d_in[3];
  const float* enc_W1 = (const float*)d_in[4];
  const float* enc_b1 = (const float*)d_in[5];
  const float* enc_W2 = (const float*)d_in[6];
  const float* enc_b2 = (const float*)d_in[7];
  const float* enc_W3 = (const float*)d_in[8];
  const float* enc_b3 = (const float*)d_in[9];
  const float* gru_Wih = (const float*)d_in[10];
  const float* gru_Whh = (const float*)d_in[11];
  const float* gru_bih = (const float*)d_in[12];
  const float* gru_bhh = (const float*)d_in[13];
  const float* post_W1 = (const float*)d_in[14];
  const float* post_b1 = (const float*)d_in[15];
  const float* post_W2 = (const float*)d_in[16];
  const float* post_b2 = (const float*)d_in[17];
  const float* post_W3 = (const float*)d_in[18];
  const float* post_b3 = (const float*)d_in[19];
  const float* dec_W1 = (const float*)d_in[20];
  const float* dec_b1 = (const float*)d_in[21];
  const float* dec_W2 = (const float*)d_in[22];
  const float* dec_b2 = (const float*)d_in[23];
  const float* dec_W3 = (const float*)d_in[24];
  const float* dec_b3 = (const float*)d_in[25];
  float* out = (float*)d_out;

  pack_kernel<<<(PK_TOTAL + 255) / 256, 256, 0, stream>>>(
      enc_W1, enc_W2, enc_W3, dec_W1, dec_W2, dec_W3);

  enc_mfma<<<Bb * 8, 256, 0, stream>>>(obs, action, enc_b1, enc_b2, enc_b3,
                                       out);

  const size_t rec_bytes = (size_t)Bb * REC_T * 12 * sizeof(float);
  if (ws_size >= rec_bytes) {
    float* rec = (float*)d_ws;
    const int total = Bb * REC_T;
    gprep_kernel<<<(total + 255) / 256, 256, 0, stream>>>(
        action, mask, gru_Wih, gru_bih, out, rec);
    scan2_kernel<<<128, 64, 0, stream>>>(rec, post_W2, post_W1, post_b1,
                                         post_b2, post_W3, post_b3, gru_Wih,
                                         gru_Whh, gru_bhh, out);
  } else {
    scan_fb_kernel<<<128, 64, 0, stream>>>(
        action, mask, gru_Wih, gru_Whh, gru_bih, gru_bhh, post_W1, post_b1,
        post_W2, post_b2, post_W3, post_b3, out);
  }

  dec_mfma<<<Bb * 8, 256, 0, stream>>>(action, dec_b1, dec_b2, dec_b3, out);
  copy_kernel<<<2048, 256, 0, stream>>>(obs, t_label, out);
}